// Round 4
// baseline (403.772 us; speedup 1.0000x reference)
//
#include <hip/hip_runtime.h>
#include <math.h>

#define L_SEQ 2048
#define DM 1024
#define DI 2048
#define DS 16
#define DTR 64
#define EPS 1e-5f

typedef float f32x4 __attribute__((ext_vector_type(4)));
typedef __bf16 bf16x8 __attribute__((ext_vector_type(8)));

static __device__ __forceinline__ unsigned short f2bf(float f) {
  union { float f; unsigned u; } v; v.f = f;
  unsigned r = v.u + 0x7fffu + ((v.u >> 16) & 1u);
  return (unsigned short)(r >> 16);
}
static __device__ __forceinline__ float bf2f(unsigned short s) {
  union { unsigned u; float f; } v; v.u = ((unsigned)s) << 16;
  return v.f;
}

// ---------------- LayerNorm -> bf16 ----------------
__global__ __launch_bounds__(256) void ln_kernel(const float* __restrict__ x,
                                                 const float* __restrict__ sc,
                                                 const float* __restrict__ bi,
                                                 unsigned short* __restrict__ xnb) {
  int row = blockIdx.x;
  int t = threadIdx.x;
  float4 xv = ((const float4*)(x + (size_t)row * DM))[t];
  float s  = xv.x + xv.y + xv.z + xv.w;
  float s2 = xv.x*xv.x + xv.y*xv.y + xv.z*xv.z + xv.w*xv.w;
  #pragma unroll
  for (int m = 32; m >= 1; m >>= 1) {
    s  += __shfl_xor(s, m);
    s2 += __shfl_xor(s2, m);
  }
  __shared__ float red[8];
  int wid = t >> 6, lane = t & 63;
  if (lane == 0) { red[wid] = s; red[4 + wid] = s2; }
  __syncthreads();
  s  = red[0] + red[1] + red[2] + red[3];
  s2 = red[4] + red[5] + red[6] + red[7];
  float mu = s * (1.f / DM);
  float var = s2 * (1.f / DM) - mu * mu;
  float rs = rsqrtf(var + EPS);
  float4 sc4 = ((const float4*)sc)[t];
  float4 bi4 = ((const float4*)bi)[t];
  ushort4 ob;
  ob.x = f2bf((xv.x - mu) * rs * sc4.x + bi4.x);
  ob.y = f2bf((xv.y - mu) * rs * sc4.y + bi4.y);
  ob.z = f2bf((xv.z - mu) * rs * sc4.z + bi4.z);
  ob.w = f2bf((xv.w - mu) * rs * sc4.w + bi4.w);
  *(ushort4*)&xnb[(size_t)row * DM + t * 4] = ob;
}

// ---------------- transpose + fp32->bf16: W[K][N] -> Wt[N][K] (64-mult dims) ----------------
__global__ __launch_bounds__(256) void trans_bf16(
    const float* __restrict__ W, unsigned short* __restrict__ Wt, int K, int N)
{
  __shared__ unsigned short s[64][80];
  int n0 = blockIdx.x * 64, k0 = blockIdx.y * 64;
  int tid = threadIdx.x;
  #pragma unroll
  for (int p = 0; p < 4; ++p) {
    int i = p * 16 + (tid >> 4);
    int j = (tid & 15) * 4;
    float4 w = *(const float4*)&W[(size_t)(k0 + i) * N + n0 + j];
    s[j + 0][i] = f2bf(w.x); s[j + 1][i] = f2bf(w.y);
    s[j + 2][i] = f2bf(w.z); s[j + 3][i] = f2bf(w.w);
  }
  __syncthreads();
  #pragma unroll
  for (int q = 0; q < 2; ++q) {
    int n = q * 32 + (tid >> 3);
    int i8 = (tid & 7) * 8;
    *(int4*)&Wt[(size_t)(n0 + n) * K + k0 + i8] = *(const int4*)&s[n][i8];
  }
}

// ---------------- W_x[2048][96] fp32 -> Wxt[128][2048] bf16 (zero-padded rows) ----------------
__global__ __launch_bounds__(256) void trans_wx(
    const float* __restrict__ Wx, unsigned short* __restrict__ Wxt)
{
  int i = blockIdx.x * 256 + threadIdx.x;   // over 128*2048
  int n = i >> 11, k = i & 2047;
  Wxt[i] = (n < 96) ? f2bf(Wx[(size_t)k * 96 + n]) : (unsigned short)0;
}

// ---------------- bf16 MFMA GEMM: C = A(MxK) @ Bt(NxK)^T ----------------
// 128x128 tile, BK=64, 256 threads = 4 waves (2x2), 4x4 16x16 frags/wave.
// XOR-swizzled LDS (write+read both swizzled), reg-prefetch of next K-tile.
// EPI: 0 = none, 2 = + R[row,col] (fp32 residual)
template<int EPI>
__global__ __launch_bounds__(256) void gemm_bf16(
    const unsigned short* __restrict__ A, int lda,   // bf16 [M][K]
    const unsigned short* __restrict__ Bt, int ldb,  // bf16 [N][K]
    float* __restrict__ C, int ldc,
    int M, int N, int K,
    const float* __restrict__ R, int ldr)
{
  __shared__ __align__(16) char sm[32768];
  char* smA = sm;
  char* smB = sm + 16384;
  int tid = threadIdx.x;
  int lane = tid & 63;
  int wid = tid >> 6;
  int wm = wid >> 1, wn = wid & 1;
  int m0 = blockIdx.y * 128, n0 = blockIdx.x * 128;

  int srow = tid >> 3;            // 0..31
  int scol = (tid & 7) * 8;       // bf16 col
  const unsigned short* pA = A  + (size_t)(m0 + srow) * lda + scol;
  const unsigned short* pB = Bt + (size_t)(n0 + srow) * ldb + scol;
  int wAddr[4];
  #pragma unroll
  for (int p = 0; p < 4; ++p) {
    int r = srow + p * 32;
    wAddr[p] = r * 128 + ((scol * 2) ^ ((r & 7) << 4));
  }

  f32x4 acc[4][4];
  #pragma unroll
  for (int m = 0; m < 4; ++m)
    #pragma unroll
    for (int n = 0; n < 4; ++n) acc[m][n] = (f32x4){0.f, 0.f, 0.f, 0.f};

  int4 ra[4], rb[4];
  int nt = K / 64;
  #pragma unroll
  for (int p = 0; p < 4; ++p) {
    ra[p] = *(const int4*)(pA + (size_t)p * 32 * lda);
    rb[p] = *(const int4*)(pB + (size_t)p * 32 * ldb);
  }

  for (int t = 0; t < nt; ++t) {
    __syncthreads();
    #pragma unroll
    for (int p = 0; p < 4; ++p) {
      *(int4*)(smA + wAddr[p]) = ra[p];
      *(int4*)(smB + wAddr[p]) = rb[p];
    }
    if (t + 1 < nt) {
      const unsigned short* qA = pA + (size_t)(t + 1) * 64;
      const unsigned short* qB = pB + (size_t)(t + 1) * 64;
      #pragma unroll
      for (int p = 0; p < 4; ++p) {
        ra[p] = *(const int4*)(qA + (size_t)p * 32 * lda);
        rb[p] = *(const int4*)(qB + (size_t)p * 32 * ldb);
      }
    }
    __syncthreads();

    bf16x8 aF[2][4], bF[2][4];
    #pragma unroll
    for (int kk = 0; kk < 2; ++kk)
      #pragma unroll
      for (int m = 0; m < 4; ++m) {
        int rA = wm * 64 + m * 16 + (lane & 15);
        int cb = kk * 64 + (lane >> 4) * 16;
        aF[kk][m] = *(const bf16x8*)(smA + rA * 128 + (cb ^ ((rA & 7) << 4)));
        int rB = wn * 64 + m * 16 + (lane & 15);
        bF[kk][m] = *(const bf16x8*)(smB + rB * 128 + (cb ^ ((rB & 7) << 4)));
      }
    #pragma unroll
    for (int kk = 0; kk < 2; ++kk)
      #pragma unroll
      for (int m = 0; m < 4; ++m)
        #pragma unroll
        for (int n = 0; n < 4; ++n)
          acc[m][n] = __builtin_amdgcn_mfma_f32_16x16x32_bf16(
              aF[kk][m], bF[kk][n], acc[m][n], 0, 0, 0);
  }

  int cm = (lane >> 4) * 4;
  int cn = lane & 15;
  #pragma unroll
  for (int m = 0; m < 4; ++m)
    #pragma unroll
    for (int n = 0; n < 4; ++n) {
      int col = n0 + wn * 64 + n * 16 + cn;
      #pragma unroll
      for (int r = 0; r < 4; ++r) {
        int row = m0 + wm * 64 + m * 16 + cm + r;
        float v = acc[m][n][r];
        if (EPI == 2) v += R[(size_t)row * ldr + col];
        C[(size_t)row * ldc + col] = v;
      }
    }
}

// ---------------- Generic fp32 GEMM (kept for delta GEMM, K=64) ----------------
template<int EPI>
__global__ __launch_bounds__(256) void gemm_f32(
    const float* __restrict__ A, int lda,
    const float* __restrict__ B, int ldb,
    float* __restrict__ C, int ldc,
    int M, int N, int K,
    const float* __restrict__ bias,
    const float* __restrict__ R, int ldr)
{
  __shared__ __align__(16) float As[16][132];
  __shared__ __align__(16) float Bs[16][64];
  int tid = threadIdx.x;
  int tx = tid & 15, ty = tid >> 4;
  int m0 = blockIdx.y * 128, n0 = blockIdx.x * 64;
  float acc[8][4];
  #pragma unroll
  for (int i = 0; i < 8; ++i)
    #pragma unroll
    for (int j = 0; j < 4; ++j) acc[i][j] = 0.f;

  for (int k0 = 0; k0 < K; k0 += 16) {
    int kk4 = (tid & 3) << 2;
    #pragma unroll
    for (int p = 0; p < 2; ++p) {
      int r = (tid >> 2) + 64 * p;
      float4 av = *(const float4*)&A[(size_t)(m0 + r) * lda + k0 + kk4];
      As[kk4 + 0][r] = av.x;
      As[kk4 + 1][r] = av.y;
      As[kk4 + 2][r] = av.z;
      As[kk4 + 3][r] = av.w;
    }
    int rb = tid >> 4;
    int c4 = (tid & 15) << 2;
    *(float4*)&Bs[rb][c4] = *(const float4*)&B[(size_t)(k0 + rb) * ldb + n0 + c4];
    __syncthreads();
    #pragma unroll
    for (int kk = 0; kk < 16; ++kk) {
      float4 a0 = *(const float4*)&As[kk][ty * 8];
      float4 a1 = *(const float4*)&As[kk][ty * 8 + 4];
      float4 b  = *(const float4*)&Bs[kk][tx * 4];
      float av[8] = {a0.x, a0.y, a0.z, a0.w, a1.x, a1.y, a1.z, a1.w};
      float bv[4] = {b.x, b.y, b.z, b.w};
      #pragma unroll
      for (int i = 0; i < 8; ++i)
        #pragma unroll
        for (int j = 0; j < 4; ++j) acc[i][j] += av[i] * bv[j];
    }
    __syncthreads();
  }

  #pragma unroll
  for (int i = 0; i < 8; ++i) {
    int row = m0 + ty * 8 + i;
    int col = n0 + tx * 4;
    float v[4];
    #pragma unroll
    for (int j = 0; j < 4; ++j) v[j] = acc[i][j];
    if (EPI == 1) {
      #pragma unroll
      for (int j = 0; j < 4; ++j) {
        float w = v[j] + bias[col + j];
        v[j] = (w > 20.f) ? w : log1pf(__expf(w));
      }
    }
    if (EPI == 2) {
      float4 r4 = *(const float4*)&R[(size_t)row * ldr + col];
      v[0] += r4.x; v[1] += r4.y; v[2] += r4.z; v[3] += r4.w;
    }
    float4 o; o.x = v[0]; o.y = v[1]; o.z = v[2]; o.w = v[3];
    *(float4*)&C[(size_t)row * ldc + col] = o;
  }
}

// ---------------- causal conv4 + SiLU -> bf16 ----------------
__global__ __launch_bounds__(256) void conv_silu_kernel(
    const float* __restrict__ xr,  // u = xr[:, :DI], row stride 2*DI
    const float* __restrict__ Wc, const float* __restrict__ bc,
    unsigned short* __restrict__ u2b)
{
  int d = blockIdx.x * 256 + threadIdx.x;
  int l = blockIdx.y;
  float acc = bc[d];
  #pragma unroll
  for (int k = 0; k < 4; ++k) {
    int ll = l + k - 3;
    if (ll >= 0) acc += xr[(size_t)ll * (2 * DI) + d] * Wc[k * DI + d];
  }
  float sig = 1.f / (1.f + __expf(-acc));
  u2b[(size_t)l * DI + d] = f2bf(acc * sig);
}

// ---------------- selective scan (bf16 u, y -> bf16) ----------------
#define CHUNK 64
__global__ __launch_bounds__(64) void scan_kernel(
    const float* __restrict__ delta, const unsigned short* __restrict__ u2b,
    const float* __restrict__ res, int ldres,
    const float* __restrict__ xdbl,
    const float* __restrict__ A_log, const float* __restrict__ Dp,
    unsigned short* __restrict__ yb, int ldyu)
{
  int t = threadIdx.x;
  int ch = t >> 4;
  int n  = t & 15;
  int d0 = blockIdx.x * 4;
  int d  = d0 + ch;

  __shared__ __align__(16) float sdT[4][68], suT[4][68];
  __shared__ __align__(16) float sBT[16][68], sCT[16][68];
  __shared__ __align__(16) float srs[CHUNK][4];
  __shared__ __align__(16) float sv[CHUNK][68];
  __shared__ __align__(16) float sy[CHUNK][4];

  float An = -__expf(A_log[d * DS + n]);
  float Dd = Dp[d];
  float h = 0.f;

  float4 rd, rr, rB[4], rC[4];
  ushort4 ru;
  auto LOAD = [&](int c0) {
    int l = c0 + t;
    rd = *(const float4*)&delta[(size_t)l * DI + d0];
    ru = *(const ushort4*)&u2b[(size_t)l * DI + d0];
    rr = *(const float4*)&res[(size_t)l * ldres + d0];
    #pragma unroll
    for (int r = 0; r < 4; ++r) {
      int ll = c0 + (t >> 2) + r * 16;
      int n4 = (t & 3) * 4;
      rB[r] = *(const float4*)&xdbl[(size_t)ll * 128 + 64 + n4];
      rC[r] = *(const float4*)&xdbl[(size_t)ll * 128 + 80 + n4];
    }
  };

  LOAD(0);
  for (int c0 = 0; c0 < L_SEQ; c0 += CHUNK) {
    __syncthreads();
    sdT[0][t] = rd.x; sdT[1][t] = rd.y; sdT[2][t] = rd.z; sdT[3][t] = rd.w;
    suT[0][t] = bf2f(ru.x); suT[1][t] = bf2f(ru.y);
    suT[2][t] = bf2f(ru.z); suT[3][t] = bf2f(ru.w);
    *(float4*)&srs[t][0] = rr;
    #pragma unroll
    for (int r = 0; r < 4; ++r) {
      int ll = (t >> 2) + r * 16;
      int nb = (t & 3) * 4;
      sBT[nb + 0][ll] = rB[r].x; sBT[nb + 1][ll] = rB[r].y;
      sBT[nb + 2][ll] = rB[r].z; sBT[nb + 3][ll] = rB[r].w;
      sCT[nb + 0][ll] = rC[r].x; sCT[nb + 1][ll] = rC[r].y;
      sCT[nb + 2][ll] = rC[r].z; sCT[nb + 3][ll] = rC[r].w;
    }
    if (c0 + CHUNK < L_SEQ) LOAD(c0 + CHUNK);
    __syncthreads();

    #pragma unroll
    for (int g = 0; g < CHUNK; g += 4) {
      float4 dl4 = *(const float4*)&sdT[ch][g];
      float4 ul4 = *(const float4*)&suT[ch][g];
      float4 Bn4 = *(const float4*)&sBT[n][g];
      float4 Cn4 = *(const float4*)&sCT[n][g];
      float dl[4] = {dl4.x, dl4.y, dl4.z, dl4.w};
      float ul[4] = {ul4.x, ul4.y, ul4.z, ul4.w};
      float Bn[4] = {Bn4.x, Bn4.y, Bn4.z, Bn4.w};
      float Cn[4] = {Cn4.x, Cn4.y, Cn4.z, Cn4.w};
      #pragma unroll
      for (int i = 0; i < 4; ++i) {
        float dA = __expf(dl[i] * An);
        h = dA * h + (dl[i] * ul[i]) * Bn[i];
        float vv = h * Cn[i];
        if (n == 0) vv += ul[i] * Dd;
        sv[g + i][t] = vv;
      }
    }
    __syncthreads();

    #pragma unroll
    for (int r = 0; r < 4; ++r) {
      int ll = (t >> 2) + r * 16;
      int c2 = t & 3;
      const float4* p = (const float4*)&sv[ll][c2 * 16];
      float4 a = p[0], b = p[1], c = p[2], e = p[3];
      float s = ((a.x + a.y) + (a.z + a.w)) + ((b.x + b.y) + (b.z + b.w))
              + ((c.x + c.y) + (c.z + c.w)) + ((e.x + e.y) + (e.z + e.w));
      float rv = srs[ll][c2];
      float sig = 1.f / (1.f + __expf(-rv));
      sy[ll][c2] = s * (rv * sig);
    }
    __syncthreads();
    float4 v = *(const float4*)&sy[t][0];
    ushort4 ob;
    ob.x = f2bf(v.x); ob.y = f2bf(v.y); ob.z = f2bf(v.z); ob.w = f2bf(v.w);
    *(ushort4*)&yb[(size_t)(c0 + t) * ldyu + d0] = ob;
  }
}

// ---------------- launch ----------------
extern "C" void kernel_launch(void* const* d_in, const int* in_sizes, int n_in,
                              void* d_out, int out_size, void* d_ws, size_t ws_size,
                              hipStream_t stream)
{
  const float* x      = (const float*)d_in[0];
  const float* W_in   = (const float*)d_in[1];
  const float* W_conv = (const float*)d_in[2];
  const float* b_conv = (const float*)d_in[3];
  const float* W_x    = (const float*)d_in[4];
  const float* W_dt   = (const float*)d_in[5];
  const float* b_dt   = (const float*)d_in[6];
  const float* A_log  = (const float*)d_in[7];
  const float* Dp     = (const float*)d_in[8];
  const float* W_out  = (const float*)d_in[9];
  const float* ln_s   = (const float*)d_in[10];
  const float* ln_b   = (const float*)d_in[11];

  char* ws = (char*)d_ws;
  unsigned short* xnb  = (unsigned short*)ws;              // 4 MB bf16 [2048][1024]
  float* xr    = (float*)(ws + (4u  << 20));               // 32 MB fp32 [2048][4096] = [u|res]
  unsigned short* u2b = (unsigned short*)(ws + (36u << 20)); // 8 MB bf16 [2048][2048]
  float* xdbl  = (float*)(ws + (44u << 20));               // 1 MB fp32 [2048][128]
  unsigned short* Wxt = (unsigned short*)(ws + (45u << 20)); // 0.5 MB bf16 [128][2048]
  float* delta = (float*)(ws + (46u << 20));               // 16 MB (ends 62 MB)
  unsigned short* Wtin  = (unsigned short*)(ws + (46u << 20)); // 8 MB, aliases delta (dead before delta GEMM)
  unsigned short* Wtout = (unsigned short*)ws;                 // 4 MB, aliases xnb (dead after GEMM1)
  float* res   = xr + DI;                                  // ld = 2*DI
  unsigned short* yb = (unsigned short*)xr;                // bf16 y in dead u-cols, ld = 4*DI ushorts

  ln_kernel<<<L_SEQ, 256, 0, stream>>>(x, ln_s, ln_b, xnb);

  trans_bf16<<<dim3((2 * DI) / 64, DM / 64), 256, 0, stream>>>(W_in, Wtin, DM, 2 * DI);

  gemm_bf16<0><<<dim3((2 * DI) / 128, L_SEQ / 128), 256, 0, stream>>>(
      xnb, DM, Wtin, DM, xr, 2 * DI, L_SEQ, 2 * DI, DM, nullptr, 0);

  conv_silu_kernel<<<dim3(DI / 256, L_SEQ), 256, 0, stream>>>(xr, W_conv, b_conv, u2b);

  trans_bf16<<<dim3(DM / 64, DI / 64), 256, 0, stream>>>(W_out, Wtout, DI, DM);

  trans_wx<<<(128 * 2048) / 256, 256, 0, stream>>>(W_x, Wxt);

  gemm_bf16<0><<<dim3(1, L_SEQ / 128), 256, 0, stream>>>(
      u2b, DI, Wxt, DI, xdbl, 128, L_SEQ, 128, DI, nullptr, 0);

  gemm_f32<1><<<dim3(DI / 64, L_SEQ / 128), 256, 0, stream>>>(
      xdbl, 128, W_dt, DI, delta, DI, L_SEQ, DI, DTR, b_dt, nullptr, 0);

  scan_kernel<<<DI / 4, 64, 0, stream>>>(
      delta, u2b, res, 2 * DI, xdbl, A_log, Dp, yb, 4 * DI);

  gemm_bf16<2><<<dim3(DM / 128, L_SEQ / 128), 256, 0, stream>>>(
      yb, 4 * DI, Wtout, DI, (float*)d_out, DM, L_SEQ, DM, DI, x, DM);
}

// Round 5
// 349.982 us; speedup vs baseline: 1.1537x; 1.1537x over previous
//
#include <hip/hip_runtime.h>
#include <math.h>

#define L_SEQ 2048
#define DM 1024
#define DI 2048
#define DS 16
#define DTR 64
#define EPS 1e-5f

typedef float f32x4 __attribute__((ext_vector_type(4)));
typedef __bf16 bf16x8 __attribute__((ext_vector_type(8)));

static __device__ __forceinline__ unsigned short f2bf(float f) {
  union { float f; unsigned u; } v; v.f = f;
  unsigned r = v.u + 0x7fffu + ((v.u >> 16) & 1u);
  return (unsigned short)(r >> 16);
}
static __device__ __forceinline__ float bf2f(unsigned short s) {
  union { unsigned u; float f; } v; v.u = ((unsigned)s) << 16;
  return v.f;
}

// ---------------- LayerNorm -> bf16 ----------------
__global__ __launch_bounds__(256) void ln_kernel(const float* __restrict__ x,
                                                 const float* __restrict__ sc,
                                                 const float* __restrict__ bi,
                                                 unsigned short* __restrict__ xnb) {
  int row = blockIdx.x;
  int t = threadIdx.x;
  float4 xv = ((const float4*)(x + (size_t)row * DM))[t];
  float s  = xv.x + xv.y + xv.z + xv.w;
  float s2 = xv.x*xv.x + xv.y*xv.y + xv.z*xv.z + xv.w*xv.w;
  #pragma unroll
  for (int m = 32; m >= 1; m >>= 1) {
    s  += __shfl_xor(s, m);
    s2 += __shfl_xor(s2, m);
  }
  __shared__ float red[8];
  int wid = t >> 6, lane = t & 63;
  if (lane == 0) { red[wid] = s; red[4 + wid] = s2; }
  __syncthreads();
  s  = red[0] + red[1] + red[2] + red[3];
  s2 = red[4] + red[5] + red[6] + red[7];
  float mu = s * (1.f / DM);
  float var = s2 * (1.f / DM) - mu * mu;
  float rs = rsqrtf(var + EPS);
  float4 sc4 = ((const float4*)sc)[t];
  float4 bi4 = ((const float4*)bi)[t];
  ushort4 ob;
  ob.x = f2bf((xv.x - mu) * rs * sc4.x + bi4.x);
  ob.y = f2bf((xv.y - mu) * rs * sc4.y + bi4.y);
  ob.z = f2bf((xv.z - mu) * rs * sc4.z + bi4.z);
  ob.w = f2bf((xv.w - mu) * rs * sc4.w + bi4.w);
  *(ushort4*)&xnb[(size_t)row * DM + t * 4] = ob;
}

// ---------------- transpose + fp32->bf16: W[K][N] -> Wt[N][K] (64-mult dims) ----------------
__global__ __launch_bounds__(256) void trans_bf16(
    const float* __restrict__ W, unsigned short* __restrict__ Wt, int K, int N)
{
  __shared__ unsigned short s[64][80];
  int n0 = blockIdx.x * 64, k0 = blockIdx.y * 64;
  int tid = threadIdx.x;
  #pragma unroll
  for (int p = 0; p < 4; ++p) {
    int i = p * 16 + (tid >> 4);
    int j = (tid & 15) * 4;
    float4 w = *(const float4*)&W[(size_t)(k0 + i) * N + n0 + j];
    s[j + 0][i] = f2bf(w.x); s[j + 1][i] = f2bf(w.y);
    s[j + 2][i] = f2bf(w.z); s[j + 3][i] = f2bf(w.w);
  }
  __syncthreads();
  #pragma unroll
  for (int q = 0; q < 2; ++q) {
    int n = q * 32 + (tid >> 3);
    int i8 = (tid & 7) * 8;
    *(int4*)&Wt[(size_t)(n0 + n) * K + k0 + i8] = *(const int4*)&s[n][i8];
  }
}

// ---------------- bf16 [R][C] -> bf16 [C][R] tile transpose ----------------
__global__ __launch_bounds__(256) void transpose_b16(
    const unsigned short* __restrict__ in, unsigned short* __restrict__ out,
    int R, int C)
{
  __shared__ unsigned short s[64][72];
  int c0 = blockIdx.x * 64, r0 = blockIdx.y * 64;
  int tid = threadIdx.x;
  #pragma unroll
  for (int p = 0; p < 2; ++p) {
    int r = p * 32 + (tid >> 3);
    int c = (tid & 7) * 8;
    *(int4*)&s[r][c] = *(const int4*)&in[(size_t)(r0 + r) * C + c0 + c];
  }
  __syncthreads();
  #pragma unroll
  for (int p = 0; p < 2; ++p) {
    int c = p * 32 + (tid >> 3);
    int r = (tid & 7) * 8;
    ushort4 a, b;
    a.x = s[r + 0][c]; a.y = s[r + 1][c]; a.z = s[r + 2][c]; a.w = s[r + 3][c];
    b.x = s[r + 4][c]; b.y = s[r + 5][c]; b.z = s[r + 6][c]; b.w = s[r + 7][c];
    *(ushort4*)&out[(size_t)(c0 + c) * R + r0 + r] = a;
    *(ushort4*)&out[(size_t)(c0 + c) * R + r0 + r + 4] = b;
  }
}

// ---------------- W_x[2048][96] fp32 -> Wxt[128][2048] bf16 (zero-padded rows) ----------------
__global__ __launch_bounds__(256) void trans_wx(
    const float* __restrict__ Wx, unsigned short* __restrict__ Wxt)
{
  int i = blockIdx.x * 256 + threadIdx.x;   // over 128*2048
  int n = i >> 11, k = i & 2047;
  Wxt[i] = (n < 96) ? f2bf(Wx[(size_t)k * 96 + n]) : (unsigned short)0;
}

// ---------------- bf16 MFMA GEMM: C = A(MxK) @ Bt(NxK)^T ----------------
// 128x128 tile, BK=64, 256 threads = 4 waves, 4x4 16x16 frags/wave.
// Split-K via gridDim.z (partials at C + z*M*ldc; EPI only valid with z==1).
// EPI: 0 none, 1 softplus(acc + bias[ROW]), 2 acc + R[row,col]
// OUTB: 0 fp32 C, 1 bf16 C
template<int EPI, int OUTB>
__global__ __launch_bounds__(256) void gemm_bf16(
    const unsigned short* __restrict__ A, int lda,
    const unsigned short* __restrict__ Bt, int ldb,
    void* __restrict__ Cv, int ldc,
    int M, int N, int K,
    const float* __restrict__ bias,
    const float* __restrict__ R, int ldr)
{
  __shared__ __align__(16) char sm[32768];
  char* smA = sm;
  char* smB = sm + 16384;
  int tid = threadIdx.x;
  int lane = tid & 63;
  int wid = tid >> 6;
  int wm = wid >> 1, wn = wid & 1;
  int m0 = blockIdx.y * 128, n0 = blockIdx.x * 128;

  int kp = K / gridDim.z;          // K-range per split
  int kb = blockIdx.z * kp;
  int nt = kp / 64;

  int srow = tid >> 3;            // 0..31
  int scol = (tid & 7) * 8;       // bf16 col within BK
  const unsigned short* pA = A  + (size_t)(m0 + srow) * lda + kb + scol;
  const unsigned short* pB = Bt + (size_t)(n0 + srow) * ldb + kb + scol;
  int wAddr[4];
  #pragma unroll
  for (int p = 0; p < 4; ++p) {
    int r = srow + p * 32;
    wAddr[p] = r * 128 + ((scol * 2) ^ ((r & 7) << 4));
  }

  f32x4 acc[4][4];
  #pragma unroll
  for (int m = 0; m < 4; ++m)
    #pragma unroll
    for (int n = 0; n < 4; ++n) acc[m][n] = (f32x4){0.f, 0.f, 0.f, 0.f};

  int4 ra[4], rb[4];
  #pragma unroll
  for (int p = 0; p < 4; ++p) {
    ra[p] = *(const int4*)(pA + (size_t)p * 32 * lda);
    rb[p] = *(const int4*)(pB + (size_t)p * 32 * ldb);
  }

  for (int t = 0; t < nt; ++t) {
    __syncthreads();
    #pragma unroll
    for (int p = 0; p < 4; ++p) {
      *(int4*)(smA + wAddr[p]) = ra[p];
      *(int4*)(smB + wAddr[p]) = rb[p];
    }
    if (t + 1 < nt) {
      const unsigned short* qA = pA + (size_t)(t + 1) * 64;
      const unsigned short* qB = pB + (size_t)(t + 1) * 64;
      #pragma unroll
      for (int p = 0; p < 4; ++p) {
        ra[p] = *(const int4*)(qA + (size_t)p * 32 * lda);
        rb[p] = *(const int4*)(qB + (size_t)p * 32 * ldb);
      }
    }
    __syncthreads();

    bf16x8 aF[2][4], bF[2][4];
    #pragma unroll
    for (int kk = 0; kk < 2; ++kk)
      #pragma unroll
      for (int m = 0; m < 4; ++m) {
        int rA = wm * 64 + m * 16 + (lane & 15);
        int cb = kk * 64 + (lane >> 4) * 16;
        aF[kk][m] = *(const bf16x8*)(smA + rA * 128 + (cb ^ ((rA & 7) << 4)));
        int rB = wn * 64 + m * 16 + (lane & 15);
        bF[kk][m] = *(const bf16x8*)(smB + rB * 128 + (cb ^ ((rB & 7) << 4)));
      }
    #pragma unroll
    for (int kk = 0; kk < 2; ++kk)
      #pragma unroll
      for (int m = 0; m < 4; ++m)
        #pragma unroll
        for (int n = 0; n < 4; ++n)
          acc[m][n] = __builtin_amdgcn_mfma_f32_16x16x32_bf16(
              aF[kk][m], bF[kk][n], acc[m][n], 0, 0, 0);
  }

  float* Cf = (float*)Cv + (size_t)blockIdx.z * M * ldc;
  unsigned short* Cb = (unsigned short*)Cv;
  int cm = (lane >> 4) * 4;
  int cn = lane & 15;
  #pragma unroll
  for (int m = 0; m < 4; ++m)
    #pragma unroll
    for (int n = 0; n < 4; ++n) {
      int col = n0 + wn * 64 + n * 16 + cn;
      #pragma unroll
      for (int r = 0; r < 4; ++r) {
        int row = m0 + wm * 64 + m * 16 + cm + r;
        float v = acc[m][n][r];
        if (EPI == 1) {
          float w = v + bias[row];
          v = (w > 20.f) ? w : log1pf(__expf(w));
        }
        if (EPI == 2) v += R[(size_t)row * ldr + col];
        if (OUTB) Cb[(size_t)row * ldc + col] = f2bf(v);
        else      Cf[(size_t)row * ldc + col] = v;
      }
    }
}

// ---------------- split-K reduce: part[8][M*128] fp32 -> xdbl bf16 ----------------
__global__ __launch_bounds__(256) void xdbl_reduce(
    const float* __restrict__ part, unsigned short* __restrict__ xdbl)
{
  int i = (blockIdx.x * 256 + threadIdx.x) * 4;   // over 2048*128
  const int SL = 2048 * 128;
  float4 s = *(const float4*)&part[i];
  #pragma unroll
  for (int z = 1; z < 8; ++z) {
    float4 p = *(const float4*)&part[(size_t)z * SL + i];
    s.x += p.x; s.y += p.y; s.z += p.z; s.w += p.w;
  }
  ushort4 ob;
  ob.x = f2bf(s.x); ob.y = f2bf(s.y); ob.z = f2bf(s.z); ob.w = f2bf(s.w);
  *(ushort4*)&xdbl[i] = ob;
}

// ---------------- causal conv4 + SiLU on transposed layout ----------------
// uT = xrT rows [0, DI), contiguous along l. One block per (d, 1024 l's).
__global__ __launch_bounds__(256) void conv_silu_kernel(
    const unsigned short* __restrict__ xrT,
    const float* __restrict__ Wc, const float* __restrict__ bc,
    unsigned short* __restrict__ u2T)
{
  int d = blockIdx.x;
  int l0 = blockIdx.y * 1024 + threadIdx.x * 4;
  const unsigned short* ur = xrT + (size_t)d * L_SEQ;
  float w0 = Wc[0 * DI + d], w1 = Wc[1 * DI + d];
  float w2 = Wc[2 * DI + d], w3 = Wc[3 * DI + d];
  float b = bc[d];
  ushort4 v0 = *(const ushort4*)&ur[l0];
  ushort4 vm; vm.x = vm.y = vm.z = vm.w = 0;
  if (l0 > 0) vm = *(const ushort4*)&ur[l0 - 4];
  float um3 = bf2f(vm.y), um2 = bf2f(vm.z), um1 = bf2f(vm.w);
  float x0 = bf2f(v0.x), x1 = bf2f(v0.y), x2 = bf2f(v0.z), x3 = bf2f(v0.w);
  float y0 = b + w0 * um3 + w1 * um2 + w2 * um1 + w3 * x0;
  float y1 = b + w0 * um2 + w1 * um1 + w2 * x0  + w3 * x1;
  float y2 = b + w0 * um1 + w1 * x0  + w2 * x1  + w3 * x2;
  float y3 = b + w0 * x0  + w1 * x1  + w2 * x2  + w3 * x3;
  ushort4 ob;
  ob.x = f2bf(y0 / (1.f + __expf(-y0)));
  ob.y = f2bf(y1 / (1.f + __expf(-y1)));
  ob.z = f2bf(y2 / (1.f + __expf(-y2)));
  ob.w = f2bf(y3 / (1.f + __expf(-y3)));
  *(ushort4*)&u2T[(size_t)d * L_SEQ + l0] = ob;
}

// ---------------- selective scan v3 (all-transposed streams) ----------------
// block = 64 threads = 4 channels x 16 states; grid = DI/4 = 512.
// deltaT fp32 [DI][L], u2T/resT bf16 [DI]/[.][L], xdbl bf16 [L][128] (L2-res),
// output ybT bf16 [DI][L]. All global streams contiguous per channel.
#define CHUNK 64
__global__ __launch_bounds__(64) void scan_kernel(
    const float* __restrict__ deltaT, const unsigned short* __restrict__ u2T,
    const unsigned short* __restrict__ resT,
    const unsigned short* __restrict__ xdbl,
    const float* __restrict__ A_log, const float* __restrict__ Dp,
    unsigned short* __restrict__ ybT)
{
  int t = threadIdx.x;
  int ch = t >> 4;
  int n  = t & 15;
  int li = (t & 15) * 4;
  int d0 = blockIdx.x * 4;
  int d  = d0 + ch;

  __shared__ __align__(16) float sdT[4][68], suT[4][68], srsT[4][68], syT[4][68];
  __shared__ __align__(16) float sBT[16][68], sCT[16][68];
  __shared__ __align__(16) float sv[CHUNK][68];

  float An = -__expf(A_log[d * DS + n]);
  float Dd = Dp[d];
  float h = 0.f;

  float4 rd;
  ushort4 ru, rr, rB[4], rC[4];
  auto LOAD = [&](int c0) {
    rd = *(const float4*)&deltaT[(size_t)d * L_SEQ + c0 + li];
    ru = *(const ushort4*)&u2T[(size_t)d * L_SEQ + c0 + li];
    rr = *(const ushort4*)&resT[(size_t)d * L_SEQ + c0 + li];
    #pragma unroll
    for (int r = 0; r < 4; ++r) {
      int ll = c0 + (t >> 2) + r * 16;
      int n4 = (t & 3) * 4;
      rB[r] = *(const ushort4*)&xdbl[(size_t)ll * 128 + 64 + n4];
      rC[r] = *(const ushort4*)&xdbl[(size_t)ll * 128 + 80 + n4];
    }
  };

  LOAD(0);
  for (int c0 = 0; c0 < L_SEQ; c0 += CHUNK) {
    __syncthreads();
    *(float4*)&sdT[ch][li] = rd;
    suT[ch][li + 0] = bf2f(ru.x); suT[ch][li + 1] = bf2f(ru.y);
    suT[ch][li + 2] = bf2f(ru.z); suT[ch][li + 3] = bf2f(ru.w);
    srsT[ch][li + 0] = bf2f(rr.x); srsT[ch][li + 1] = bf2f(rr.y);
    srsT[ch][li + 2] = bf2f(rr.z); srsT[ch][li + 3] = bf2f(rr.w);
    #pragma unroll
    for (int r = 0; r < 4; ++r) {
      int ll = (t >> 2) + r * 16;
      int nb = (t & 3) * 4;
      sBT[nb + 0][ll] = bf2f(rB[r].x); sBT[nb + 1][ll] = bf2f(rB[r].y);
      sBT[nb + 2][ll] = bf2f(rB[r].z); sBT[nb + 3][ll] = bf2f(rB[r].w);
      sCT[nb + 0][ll] = bf2f(rC[r].x); sCT[nb + 1][ll] = bf2f(rC[r].y);
      sCT[nb + 2][ll] = bf2f(rC[r].z); sCT[nb + 3][ll] = bf2f(rC[r].w);
    }
    if (c0 + CHUNK < L_SEQ) LOAD(c0 + CHUNK);
    __syncthreads();

    #pragma unroll
    for (int g = 0; g < CHUNK; g += 4) {
      float4 dl4 = *(const float4*)&sdT[ch][g];
      float4 ul4 = *(const float4*)&suT[ch][g];
      float4 Bn4 = *(const float4*)&sBT[n][g];
      float4 Cn4 = *(const float4*)&sCT[n][g];
      float dl[4] = {dl4.x, dl4.y, dl4.z, dl4.w};
      float ul[4] = {ul4.x, ul4.y, ul4.z, ul4.w};
      float Bn[4] = {Bn4.x, Bn4.y, Bn4.z, Bn4.w};
      float Cn[4] = {Cn4.x, Cn4.y, Cn4.z, Cn4.w};
      #pragma unroll
      for (int i = 0; i < 4; ++i) {
        float dA = __expf(dl[i] * An);
        h = dA * h + (dl[i] * ul[i]) * Bn[i];
        float vv = h * Cn[i];
        if (n == 0) vv += ul[i] * Dd;
        sv[g + i][t] = vv;
      }
    }
    __syncthreads();

    #pragma unroll
    for (int r = 0; r < 4; ++r) {
      int ll = (t >> 2) + r * 16;
      int c2 = t & 3;
      const float4* p = (const float4*)&sv[ll][c2 * 16];
      float4 a = p[0], b = p[1], c = p[2], e = p[3];
      float s = ((a.x + a.y) + (a.z + a.w)) + ((b.x + b.y) + (b.z + b.w))
              + ((c.x + c.y) + (c.z + c.w)) + ((e.x + e.y) + (e.z + e.w));
      float rv = srsT[c2][ll];
      float sig = 1.f / (1.f + __expf(-rv));
      syT[c2][ll] = s * (rv * sig);
    }
    __syncthreads();
    float4 v = *(const float4*)&syT[ch][li];
    ushort4 ob;
    ob.x = f2bf(v.x); ob.y = f2bf(v.y); ob.z = f2bf(v.z); ob.w = f2bf(v.w);
    *(ushort4*)&ybT[(size_t)d * L_SEQ + c0 + li] = ob;
  }
}

// ---------------- launch ----------------
extern "C" void kernel_launch(void* const* d_in, const int* in_sizes, int n_in,
                              void* d_out, int out_size, void* d_ws, size_t ws_size,
                              hipStream_t stream)
{
  const float* x      = (const float*)d_in[0];
  const float* W_in   = (const float*)d_in[1];
  const float* W_conv = (const float*)d_in[2];
  const float* b_conv = (const float*)d_in[3];
  const float* W_x    = (const float*)d_in[4];
  const float* W_dt   = (const float*)d_in[5];
  const float* b_dt   = (const float*)d_in[6];
  const float* A_log  = (const float*)d_in[7];
  const float* Dp     = (const float*)d_in[8];
  const float* W_out  = (const float*)d_in[9];
  const float* ln_s   = (const float*)d_in[10];
  const float* ln_b   = (const float*)d_in[11];

  char* ws = (char*)d_ws;
  const size_t MB = 1u << 20;
  unsigned short* xnb   = (unsigned short*)(ws);              // 4 MB
  unsigned short* xrT   = (unsigned short*)(ws + 4 * MB);     // 16 MB bf16 [4096][2048]
  unsigned short* u2T   = (unsigned short*)(ws + 20 * MB);    // 8 MB bf16 [2048][2048]
  unsigned short* u2b   = (unsigned short*)(ws + 28 * MB);    // 8 MB bf16 [2048][2048]
  unsigned short* xdbl  = (unsigned short*)(ws + 36 * MB);    // 0.5 MB bf16 [2048][128]
  unsigned short* Wxt   = (unsigned short*)(ws + 36 * MB + 512 * 1024); // 0.5 MB
  unsigned short* Wdt_t = (unsigned short*)(ws + 37 * MB);    // 0.25 MB bf16 [2048][64]
  float*          deltaT= (float*)(ws + 38 * MB);             // 16 MB fp32 [2048][2048]
  unsigned short* Wtin  = (unsigned short*)(ws + 38 * MB);    // 8 MB, aliases deltaT (dead after GEMM1)
  float*          part  = (float*)(ws + 54 * MB);             // 8 MB fp32 [8][2048*128]
  unsigned short* ybT   = (unsigned short*)(ws + 54 * MB);    // 8 MB, aliases part (part dead by scan)
  unsigned short* yb    = (unsigned short*)(ws + 62 * MB);    // 8 MB  (ends at 70 MB)
  unsigned short* Wtout = xnb;                                 // 4 MB, aliases xnb (dead after GEMM1)
  const unsigned short* resT = xrT + (size_t)DI * L_SEQ;      // rows [2048,4096)

  ln_kernel<<<L_SEQ, 256, 0, stream>>>(x, ln_s, ln_b, xnb);

  trans_bf16<<<dim3((2 * DI) / 64, DM / 64), 256, 0, stream>>>(W_in, Wtin, DM, 2 * DI);

  // xr^T [4096][2048] bf16 = (xn @ W_in)^T
  gemm_bf16<0, 1><<<dim3(L_SEQ / 128, (2 * DI) / 128), 256, 0, stream>>>(
      Wtin, DM, xnb, DM, xrT, L_SEQ, 2 * DI, L_SEQ, DM, nullptr, nullptr, 0);

  conv_silu_kernel<<<dim3(DI, 2), 256, 0, stream>>>(xrT, W_conv, b_conv, u2T);

  transpose_b16<<<dim3(L_SEQ / 64, DI / 64), 256, 0, stream>>>(u2T, u2b, DI, L_SEQ);

  trans_wx<<<(128 * 2048) / 256, 256, 0, stream>>>(W_x, Wxt);

  // x_dbl partials: split-K x8, C = part[z]
  gemm_bf16<0, 0><<<dim3(1, L_SEQ / 128, 8), 256, 0, stream>>>(
      u2b, DI, Wxt, DI, part, 128, L_SEQ, 128, DI, nullptr, nullptr, 0);

  xdbl_reduce<<<(L_SEQ * 128) / 1024, 256, 0, stream>>>(part, xdbl);

  trans_bf16<<<dim3(DI / 64, DTR / 64), 256, 0, stream>>>(W_dt, Wdt_t, DTR, DI);

  // delta^T [DI][L] fp32 = softplus(W_dt^T @ dt^T + b_dt[row])
  gemm_bf16<1, 0><<<dim3(L_SEQ / 128, DI / 128), 256, 0, stream>>>(
      Wdt_t, DTR, xdbl, 128, deltaT, L_SEQ, DI, L_SEQ, DTR, b_dt, nullptr, 0);

  trans_bf16<<<dim3(DM / 64, DI / 64), 256, 0, stream>>>(W_out, Wtout, DI, DM);

  scan_kernel<<<DI / 4, 64, 0, stream>>>(
      deltaT, u2T, resT, xdbl, A_log, Dp, ybT);

  transpose_b16<<<dim3(L_SEQ / 64, DI / 64), 256, 0, stream>>>(ybT, yb, DI, L_SEQ);

  gemm_bf16<2, 0><<<dim3(DM / 128, L_SEQ / 128), 256, 0, stream>>>(
      yb, DI, Wtout, DI, d_out, DM, L_SEQ, DM, DI, nullptr, x, DM);
}

// Round 6
// 312.656 us; speedup vs baseline: 1.2914x; 1.1194x over previous
//
#include <hip/hip_runtime.h>
#include <math.h>

#define L_SEQ 2048
#define DM 1024
#define DI 2048
#define DS 16
#define DTR 64
#define EPS 1e-5f
#define NSEG 16
#define SEGLEN 128

typedef float f32x4 __attribute__((ext_vector_type(4)));
typedef __bf16 bf16x8 __attribute__((ext_vector_type(8)));
typedef _Float16 h16x4 __attribute__((ext_vector_type(4)));

static __device__ __forceinline__ unsigned short f2bf(float f) {
  union { float f; unsigned u; } v; v.f = f;
  unsigned r = v.u + 0x7fffu + ((v.u >> 16) & 1u);
  return (unsigned short)(r >> 16);
}
static __device__ __forceinline__ float bf2f(unsigned short s) {
  union { unsigned u; float f; } v; v.u = ((unsigned)s) << 16;
  return v.f;
}

// ---------------- LayerNorm -> bf16 ----------------
__global__ __launch_bounds__(256) void ln_kernel(const float* __restrict__ x,
                                                 const float* __restrict__ sc,
                                                 const float* __restrict__ bi,
                                                 unsigned short* __restrict__ xnb) {
  int row = blockIdx.x;
  int t = threadIdx.x;
  float4 xv = ((const float4*)(x + (size_t)row * DM))[t];
  float s  = xv.x + xv.y + xv.z + xv.w;
  float s2 = xv.x*xv.x + xv.y*xv.y + xv.z*xv.z + xv.w*xv.w;
  #pragma unroll
  for (int m = 32; m >= 1; m >>= 1) {
    s  += __shfl_xor(s, m);
    s2 += __shfl_xor(s2, m);
  }
  __shared__ float red[8];
  int wid = t >> 6, lane = t & 63;
  if (lane == 0) { red[wid] = s; red[4 + wid] = s2; }
  __syncthreads();
  s  = red[0] + red[1] + red[2] + red[3];
  s2 = red[4] + red[5] + red[6] + red[7];
  float mu = s * (1.f / DM);
  float var = s2 * (1.f / DM) - mu * mu;
  float rs = rsqrtf(var + EPS);
  float4 sc4 = ((const float4*)sc)[t];
  float4 bi4 = ((const float4*)bi)[t];
  ushort4 ob;
  ob.x = f2bf((xv.x - mu) * rs * sc4.x + bi4.x);
  ob.y = f2bf((xv.y - mu) * rs * sc4.y + bi4.y);
  ob.z = f2bf((xv.z - mu) * rs * sc4.z + bi4.z);
  ob.w = f2bf((xv.w - mu) * rs * sc4.w + bi4.w);
  *(ushort4*)&xnb[(size_t)row * DM + t * 4] = ob;
}

// ---------------- transpose + fp32->bf16: W[K][N] -> Wt[N][K] (64-mult dims) ----------------
__global__ __launch_bounds__(256) void trans_bf16(
    const float* __restrict__ W, unsigned short* __restrict__ Wt, int K, int N)
{
  __shared__ unsigned short s[64][80];
  int n0 = blockIdx.x * 64, k0 = blockIdx.y * 64;
  int tid = threadIdx.x;
  #pragma unroll
  for (int p = 0; p < 4; ++p) {
    int i = p * 16 + (tid >> 4);
    int j = (tid & 15) * 4;
    float4 w = *(const float4*)&W[(size_t)(k0 + i) * N + n0 + j];
    s[j + 0][i] = f2bf(w.x); s[j + 1][i] = f2bf(w.y);
    s[j + 2][i] = f2bf(w.z); s[j + 3][i] = f2bf(w.w);
  }
  __syncthreads();
  #pragma unroll
  for (int q = 0; q < 2; ++q) {
    int n = q * 32 + (tid >> 3);
    int i8 = (tid & 7) * 8;
    *(int4*)&Wt[(size_t)(n0 + n) * K + k0 + i8] = *(const int4*)&s[n][i8];
  }
}

// ---------------- bf16 [R][C] -> bf16 [C][R] tile transpose ----------------
__global__ __launch_bounds__(256) void transpose_b16(
    const unsigned short* __restrict__ in, unsigned short* __restrict__ out,
    int R, int C)
{
  __shared__ unsigned short s[64][72];
  int c0 = blockIdx.x * 64, r0 = blockIdx.y * 64;
  int tid = threadIdx.x;
  #pragma unroll
  for (int p = 0; p < 2; ++p) {
    int r = p * 32 + (tid >> 3);
    int c = (tid & 7) * 8;
    *(int4*)&s[r][c] = *(const int4*)&in[(size_t)(r0 + r) * C + c0 + c];
  }
  __syncthreads();
  #pragma unroll
  for (int p = 0; p < 2; ++p) {
    int c = p * 32 + (tid >> 3);
    int r = (tid & 7) * 8;
    ushort4 a, b;
    a.x = s[r + 0][c]; a.y = s[r + 1][c]; a.z = s[r + 2][c]; a.w = s[r + 3][c];
    b.x = s[r + 4][c]; b.y = s[r + 5][c]; b.z = s[r + 6][c]; b.w = s[r + 7][c];
    *(ushort4*)&out[(size_t)(c0 + c) * R + r0 + r] = a;
    *(ushort4*)&out[(size_t)(c0 + c) * R + r0 + r + 4] = b;
  }
}

// ---------------- W_x[2048][96] fp32 -> Wxt[128][2048] bf16 (zero-padded rows) ----------------
__global__ __launch_bounds__(256) void trans_wx(
    const float* __restrict__ Wx, unsigned short* __restrict__ Wxt)
{
  int i = blockIdx.x * 256 + threadIdx.x;   // over 128*2048
  int n = i >> 11, k = i & 2047;
  Wxt[i] = (n < 96) ? f2bf(Wx[(size_t)k * 96 + n]) : (unsigned short)0;
}

// ---------------- bf16 MFMA GEMM: C = A(MxK) @ Bt(NxK)^T ----------------
// 128x128 tile, BK=64, 256 threads = 4 waves, 4x4 16x16 frags/wave.
// Split-K via gridDim.z (partials at C + z*M*ldc; EPI only valid with z==1).
// EPI: 0 none, 1 softplus(acc + bias[ROW]), 2 acc + R[row,col]
// OUTB: 0 fp32 C, 1 bf16 C
template<int EPI, int OUTB>
__global__ __launch_bounds__(256) void gemm_bf16(
    const unsigned short* __restrict__ A, int lda,
    const unsigned short* __restrict__ Bt, int ldb,
    void* __restrict__ Cv, int ldc,
    int M, int N, int K,
    const float* __restrict__ bias,
    const float* __restrict__ R, int ldr)
{
  __shared__ __align__(16) char sm[32768];
  char* smA = sm;
  char* smB = sm + 16384;
  int tid = threadIdx.x;
  int lane = tid & 63;
  int wid = tid >> 6;
  int wm = wid >> 1, wn = wid & 1;
  int m0 = blockIdx.y * 128, n0 = blockIdx.x * 128;

  int kp = K / gridDim.z;          // K-range per split
  int kb = blockIdx.z * kp;
  int nt = kp / 64;

  int srow = tid >> 3;            // 0..31
  int scol = (tid & 7) * 8;       // bf16 col within BK
  const unsigned short* pA = A  + (size_t)(m0 + srow) * lda + kb + scol;
  const unsigned short* pB = Bt + (size_t)(n0 + srow) * ldb + kb + scol;
  int wAddr[4];
  #pragma unroll
  for (int p = 0; p < 4; ++p) {
    int r = srow + p * 32;
    wAddr[p] = r * 128 + ((scol * 2) ^ ((r & 7) << 4));
  }

  f32x4 acc[4][4];
  #pragma unroll
  for (int m = 0; m < 4; ++m)
    #pragma unroll
    for (int n = 0; n < 4; ++n) acc[m][n] = (f32x4){0.f, 0.f, 0.f, 0.f};

  int4 ra[4], rb[4];
  #pragma unroll
  for (int p = 0; p < 4; ++p) {
    ra[p] = *(const int4*)(pA + (size_t)p * 32 * lda);
    rb[p] = *(const int4*)(pB + (size_t)p * 32 * ldb);
  }

  for (int t = 0; t < nt; ++t) {
    __syncthreads();
    #pragma unroll
    for (int p = 0; p < 4; ++p) {
      *(int4*)(smA + wAddr[p]) = ra[p];
      *(int4*)(smB + wAddr[p]) = rb[p];
    }
    if (t + 1 < nt) {
      const unsigned short* qA = pA + (size_t)(t + 1) * 64;
      const unsigned short* qB = pB + (size_t)(t + 1) * 64;
      #pragma unroll
      for (int p = 0; p < 4; ++p) {
        ra[p] = *(const int4*)(qA + (size_t)p * 32 * lda);
        rb[p] = *(const int4*)(qB + (size_t)p * 32 * ldb);
      }
    }
    __syncthreads();

    bf16x8 aF[2][4], bF[2][4];
    #pragma unroll
    for (int kk = 0; kk < 2; ++kk)
      #pragma unroll
      for (int m = 0; m < 4; ++m) {
        int rA = wm * 64 + m * 16 + (lane & 15);
        int cb = kk * 64 + (lane >> 4) * 16;
        aF[kk][m] = *(const bf16x8*)(smA + rA * 128 + (cb ^ ((rA & 7) << 4)));
        int rB = wn * 64 + m * 16 + (lane & 15);
        bF[kk][m] = *(const bf16x8*)(smB + rB * 128 + (cb ^ ((rB & 7) << 4)));
      }
    #pragma unroll
    for (int kk = 0; kk < 2; ++kk)
      #pragma unroll
      for (int m = 0; m < 4; ++m)
        #pragma unroll
        for (int n = 0; n < 4; ++n)
          acc[m][n] = __builtin_amdgcn_mfma_f32_16x16x32_bf16(
              aF[kk][m], bF[kk][n], acc[m][n], 0, 0, 0);
  }

  float* Cf = (float*)Cv + (size_t)blockIdx.z * M * ldc;
  unsigned short* Cb = (unsigned short*)Cv;
  int cm = (lane >> 4) * 4;
  int cn = lane & 15;
  #pragma unroll
  for (int m = 0; m < 4; ++m)
    #pragma unroll
    for (int n = 0; n < 4; ++n) {
      int col = n0 + wn * 64 + n * 16 + cn;
      #pragma unroll
      for (int r = 0; r < 4; ++r) {
        int row = m0 + wm * 64 + m * 16 + cm + r;
        float v = acc[m][n][r];
        if (EPI == 1) {
          float w = v + bias[row];
          v = (w > 20.f) ? w : log1pf(__expf(w));
        }
        if (EPI == 2) v += R[(size_t)row * ldr + col];
        if (OUTB) Cb[(size_t)row * ldc + col] = f2bf(v);
        else      Cf[(size_t)row * ldc + col] = v;
      }
    }
}

// ---------------- split-K reduce: part[8][M*128] fp32 -> xdbl bf16 ----------------
__global__ __launch_bounds__(256) void xdbl_reduce(
    const float* __restrict__ part, unsigned short* __restrict__ xdbl)
{
  int i = (blockIdx.x * 256 + threadIdx.x) * 4;   // over 2048*128
  const int SL = 2048 * 128;
  float4 s = *(const float4*)&part[i];
  #pragma unroll
  for (int z = 1; z < 8; ++z) {
    float4 p = *(const float4*)&part[(size_t)z * SL + i];
    s.x += p.x; s.y += p.y; s.z += p.z; s.w += p.w;
  }
  ushort4 ob;
  ob.x = f2bf(s.x); ob.y = f2bf(s.y); ob.z = f2bf(s.z); ob.w = f2bf(s.w);
  *(ushort4*)&xdbl[i] = ob;
}

// ---------------- causal conv4 + SiLU on transposed layout ----------------
__global__ __launch_bounds__(256) void conv_silu_kernel(
    const unsigned short* __restrict__ xrT,
    const float* __restrict__ Wc, const float* __restrict__ bc,
    unsigned short* __restrict__ u2T)
{
  int d = blockIdx.x;
  int l0 = blockIdx.y * 1024 + threadIdx.x * 4;
  const unsigned short* ur = xrT + (size_t)d * L_SEQ;
  float w0 = Wc[0 * DI + d], w1 = Wc[1 * DI + d];
  float w2 = Wc[2 * DI + d], w3 = Wc[3 * DI + d];
  float b = bc[d];
  ushort4 v0 = *(const ushort4*)&ur[l0];
  ushort4 vm; vm.x = vm.y = vm.z = vm.w = 0;
  if (l0 > 0) vm = *(const ushort4*)&ur[l0 - 4];
  float um3 = bf2f(vm.y), um2 = bf2f(vm.z), um1 = bf2f(vm.w);
  float x0 = bf2f(v0.x), x1 = bf2f(v0.y), x2 = bf2f(v0.z), x3 = bf2f(v0.w);
  float y0 = b + w0 * um3 + w1 * um2 + w2 * um1 + w3 * x0;
  float y1 = b + w0 * um2 + w1 * um1 + w2 * x0  + w3 * x1;
  float y2 = b + w0 * um1 + w1 * x0  + w2 * x1  + w3 * x2;
  float y3 = b + w0 * x0  + w1 * x1  + w2 * x2  + w3 * x3;
  ushort4 ob;
  ob.x = f2bf(y0 / (1.f + __expf(-y0)));
  ob.y = f2bf(y1 / (1.f + __expf(-y1)));
  ob.z = f2bf(y2 / (1.f + __expf(-y2)));
  ob.w = f2bf(y3 / (1.f + __expf(-y3)));
  *(ushort4*)&u2T[(size_t)d * L_SEQ + l0] = ob;
}

// ================= segmented selective scan =================
// Scalar linear recurrences h_t = dA_t h_{t-1} + dBu_t for (d,n) in DIxDS.
// L split into NSEG segments of SEGLEN. Pass1: per-segment (prod dA, h_end | h0=0).
// Pass3: reconstruct h_in from segment summaries (<=15 fma), run full scan + y.

// ---- pass 1: segment summaries ----
__global__ __launch_bounds__(64) void scan_pass1(
    const float* __restrict__ deltaT, const unsigned short* __restrict__ u2T,
    const unsigned short* __restrict__ xdbl,
    const float* __restrict__ A_log,
    float* __restrict__ hend, float* __restrict__ aprod)
{
  int t = threadIdx.x;
  int ch = t >> 4, n = t & 15;
  int li = (t & 15) * 4;
  int d0 = blockIdx.x * 4, d = d0 + ch;
  int s = blockIdx.y;
  int base = s * SEGLEN;

  __shared__ __align__(16) float sdT[4][68], suT[4][68], sBT[16][68];

  float An = -__expf(A_log[d * DS + n]);
  float h = 0.f, P = 1.f;

  float4 rd; ushort4 ru; ushort4 rB[4];
  auto LOAD = [&](int c0) {
    rd = *(const float4*)&deltaT[(size_t)d * L_SEQ + c0 + li];
    ru = *(const ushort4*)&u2T[(size_t)d * L_SEQ + c0 + li];
    #pragma unroll
    for (int r = 0; r < 4; ++r) {
      int ll = c0 + (t >> 2) + r * 16;
      rB[r] = *(const ushort4*)&xdbl[(size_t)ll * 128 + 64 + (t & 3) * 4];
    }
  };

  LOAD(base);
  for (int cc = 0; cc < 2; ++cc) {
    __syncthreads();
    *(float4*)&sdT[ch][li] = rd;
    suT[ch][li + 0] = bf2f(ru.x); suT[ch][li + 1] = bf2f(ru.y);
    suT[ch][li + 2] = bf2f(ru.z); suT[ch][li + 3] = bf2f(ru.w);
    #pragma unroll
    for (int r = 0; r < 4; ++r) {
      int ll = (t >> 2) + r * 16;
      int nb = (t & 3) * 4;
      sBT[nb + 0][ll] = bf2f(rB[r].x); sBT[nb + 1][ll] = bf2f(rB[r].y);
      sBT[nb + 2][ll] = bf2f(rB[r].z); sBT[nb + 3][ll] = bf2f(rB[r].w);
    }
    if (cc == 0) LOAD(base + 64);
    __syncthreads();

    #pragma unroll
    for (int g = 0; g < 64; g += 4) {
      float4 dl4 = *(const float4*)&sdT[ch][g];
      float4 ul4 = *(const float4*)&suT[ch][g];
      float4 Bn4 = *(const float4*)&sBT[n][g];
      float dl[4] = {dl4.x, dl4.y, dl4.z, dl4.w};
      float ul[4] = {ul4.x, ul4.y, ul4.z, ul4.w};
      float Bn[4] = {Bn4.x, Bn4.y, Bn4.z, Bn4.w};
      #pragma unroll
      for (int i = 0; i < 4; ++i) {
        float dA = __expf(dl[i] * An);
        P *= dA;
        h = dA * h + (dl[i] * ul[i]) * Bn[i];
      }
    }
  }
  size_t idx = (size_t)s * (DI * DS) + d0 * DS + t;
  hend[idx]  = h;
  aprod[idx] = P;
}

// ---- pass 3: full scan per segment with stitched h_in ----
__global__ __launch_bounds__(64) void scan_pass3(
    const float* __restrict__ deltaT, const unsigned short* __restrict__ u2T,
    const unsigned short* __restrict__ resT,
    const unsigned short* __restrict__ xdbl,
    const float* __restrict__ A_log, const float* __restrict__ Dp,
    const float* __restrict__ hend, const float* __restrict__ aprod,
    unsigned short* __restrict__ ybT)
{
  int t = threadIdx.x;
  int ch = t >> 4, n = t & 15;
  int li = (t & 15) * 4;
  int d0 = blockIdx.x * 4, d = d0 + ch;
  int s = blockIdx.y;
  int base = s * SEGLEN;

  __shared__ __align__(16) float sdT[4][68], suT[4][68];
  __shared__ __align__(16) float sBT[16][68], sCT[16][68];
  __shared__ __align__(16) _Float16 svh[64][68];

  float An = -__expf(A_log[d * DS + n]);
  float Dd = Dp[d];

  // stitch: h_in for this segment from prior segment summaries
  float h = 0.f;
  int fi = d0 * DS + t;
  for (int k = 0; k < s; ++k)
    h = aprod[(size_t)k * (DI * DS) + fi] * h + hend[(size_t)k * (DI * DS) + fi];

  float4 rd; ushort4 ru, rB[4], rC[4];
  auto LOAD = [&](int c0) {
    rd = *(const float4*)&deltaT[(size_t)d * L_SEQ + c0 + li];
    ru = *(const ushort4*)&u2T[(size_t)d * L_SEQ + c0 + li];
    #pragma unroll
    for (int r = 0; r < 4; ++r) {
      int ll = c0 + (t >> 2) + r * 16;
      int n4 = (t & 3) * 4;
      rB[r] = *(const ushort4*)&xdbl[(size_t)ll * 128 + 64 + n4];
      rC[r] = *(const ushort4*)&xdbl[(size_t)ll * 128 + 80 + n4];
    }
  };

  LOAD(base);
  for (int cc = 0; cc < 2; ++cc) {
    int c0 = base + cc * 64;
    __syncthreads();
    *(float4*)&sdT[ch][li] = rd;
    suT[ch][li + 0] = bf2f(ru.x); suT[ch][li + 1] = bf2f(ru.y);
    suT[ch][li + 2] = bf2f(ru.z); suT[ch][li + 3] = bf2f(ru.w);
    #pragma unroll
    for (int r = 0; r < 4; ++r) {
      int ll = (t >> 2) + r * 16;
      int nb = (t & 3) * 4;
      sBT[nb + 0][ll] = bf2f(rB[r].x); sBT[nb + 1][ll] = bf2f(rB[r].y);
      sBT[nb + 2][ll] = bf2f(rB[r].z); sBT[nb + 3][ll] = bf2f(rB[r].w);
      sCT[nb + 0][ll] = bf2f(rC[r].x); sCT[nb + 1][ll] = bf2f(rC[r].y);
      sCT[nb + 2][ll] = bf2f(rC[r].z); sCT[nb + 3][ll] = bf2f(rC[r].w);
    }
    if (cc == 0) LOAD(base + 64);
    __syncthreads();

    #pragma unroll
    for (int g = 0; g < 64; g += 4) {
      float4 dl4 = *(const float4*)&sdT[ch][g];
      float4 ul4 = *(const float4*)&suT[ch][g];
      float4 Bn4 = *(const float4*)&sBT[n][g];
      float4 Cn4 = *(const float4*)&sCT[n][g];
      float dl[4] = {dl4.x, dl4.y, dl4.z, dl4.w};
      float ul[4] = {ul4.x, ul4.y, ul4.z, ul4.w};
      float Bn[4] = {Bn4.x, Bn4.y, Bn4.z, Bn4.w};
      float Cn[4] = {Cn4.x, Cn4.y, Cn4.z, Cn4.w};
      #pragma unroll
      for (int i = 0; i < 4; ++i) {
        float dA = __expf(dl[i] * An);
        h = dA * h + (dl[i] * ul[i]) * Bn[i];
        float vv = h * Cn[i];
        if (n == 0) vv += ul[i] * Dd;
        svh[g + i][t] = (_Float16)vv;
      }
    }
    __syncthreads();

    // post-pass: reduce 16 states (fp16 in LDS), gate with res, store y
    #pragma unroll
    for (int r = 0; r < 4; ++r) {
      int ll = (t >> 2) + r * 16;
      int c2 = t & 3;
      const h16x4* p = (const h16x4*)&svh[ll][c2 * 16];
      h16x4 a = p[0], b = p[1], c = p[2], e = p[3];
      float sA = ((float)a.x + (float)a.y) + ((float)a.z + (float)a.w);
      float sB = ((float)b.x + (float)b.y) + ((float)b.z + (float)b.w);
      float sC = ((float)c.x + (float)c.y) + ((float)c.z + (float)c.w);
      float sE = ((float)e.x + (float)e.y) + ((float)e.z + (float)e.w);
      float sum = (sA + sB) + (sC + sE);
      float rv = bf2f(resT[(size_t)(d0 + c2) * L_SEQ + c0 + ll]);
      float sig = 1.f / (1.f + __expf(-rv));
      ybT[(size_t)(d0 + c2) * L_SEQ + c0 + ll] = f2bf(sum * rv * sig);
    }
  }
}

// ---------------- launch ----------------
extern "C" void kernel_launch(void* const* d_in, const int* in_sizes, int n_in,
                              void* d_out, int out_size, void* d_ws, size_t ws_size,
                              hipStream_t stream)
{
  const float* x      = (const float*)d_in[0];
  const float* W_in   = (const float*)d_in[1];
  const float* W_conv = (const float*)d_in[2];
  const float* b_conv = (const float*)d_in[3];
  const float* W_x    = (const float*)d_in[4];
  const float* W_dt   = (const float*)d_in[5];
  const float* b_dt   = (const float*)d_in[6];
  const float* A_log  = (const float*)d_in[7];
  const float* Dp     = (const float*)d_in[8];
  const float* W_out  = (const float*)d_in[9];
  const float* ln_s   = (const float*)d_in[10];
  const float* ln_b   = (const float*)d_in[11];

  char* ws = (char*)d_ws;
  const size_t MB = 1u << 20;
  unsigned short* xnb   = (unsigned short*)(ws);              // 4 MB
  unsigned short* xrT   = (unsigned short*)(ws + 4 * MB);     // 16 MB bf16 [4096][2048]
  unsigned short* u2T   = (unsigned short*)(ws + 20 * MB);    // 8 MB bf16 [2048][2048]
  unsigned short* u2b   = (unsigned short*)(ws + 28 * MB);    // 8 MB bf16 (dead after xdbl GEMM)
  float*          hend  = (float*)(ws + 28 * MB);             // 2 MB, aliases u2b
  float*          aprod = (float*)(ws + 30 * MB);             // 2 MB, aliases u2b
  unsigned short* xdbl  = (unsigned short*)(ws + 36 * MB);    // 0.5 MB bf16 [2048][128]
  unsigned short* Wxt   = (unsigned short*)(ws + 36 * MB + 512 * 1024); // 0.5 MB
  unsigned short* Wdt_t = (unsigned short*)(ws + 37 * MB);    // 0.25 MB bf16 [2048][64]
  float*          deltaT= (float*)(ws + 38 * MB);             // 16 MB fp32 [2048][2048]
  unsigned short* Wtin  = (unsigned short*)(ws + 38 * MB);    // 8 MB, aliases deltaT (dead after GEMM1)
  float*          part  = (float*)(ws + 54 * MB);             // 8 MB fp32 [8][2048*128]
  unsigned short* ybT   = (unsigned short*)(ws + 54 * MB);    // 8 MB, aliases part (part dead by scan)
  unsigned short* yb    = (unsigned short*)(ws + 62 * MB);    // 8 MB  (ends at 70 MB)
  unsigned short* Wtout = xnb;                                 // 4 MB, aliases xnb (dead after GEMM1)
  const unsigned short* resT = xrT + (size_t)DI * L_SEQ;      // rows [2048,4096)

  ln_kernel<<<L_SEQ, 256, 0, stream>>>(x, ln_s, ln_b, xnb);

  trans_bf16<<<dim3((2 * DI) / 64, DM / 64), 256, 0, stream>>>(W_in, Wtin, DM, 2 * DI);

  // xr^T [4096][2048] bf16 = (xn @ W_in)^T
  gemm_bf16<0, 1><<<dim3(L_SEQ / 128, (2 * DI) / 128), 256, 0, stream>>>(
      Wtin, DM, xnb, DM, xrT, L_SEQ, 2 * DI, L_SEQ, DM, nullptr, nullptr, 0);

  conv_silu_kernel<<<dim3(DI, 2), 256, 0, stream>>>(xrT, W_conv, b_conv, u2T);

  transpose_b16<<<dim3(L_SEQ / 64, DI / 64), 256, 0, stream>>>(u2T, u2b, DI, L_SEQ);

  trans_wx<<<(128 * 2048) / 256, 256, 0, stream>>>(W_x, Wxt);

  // x_dbl partials: split-K x8, C = part[z]
  gemm_bf16<0, 0><<<dim3(1, L_SEQ / 128, 8), 256, 0, stream>>>(
      u2b, DI, Wxt, DI, part, 128, L_SEQ, 128, DI, nullptr, nullptr, 0);

  xdbl_reduce<<<(L_SEQ * 128) / 1024, 256, 0, stream>>>(part, xdbl);

  trans_bf16<<<dim3(DI / 64, DTR / 64), 256, 0, stream>>>(W_dt, Wdt_t, DTR, DI);

  // delta^T [DI][L] fp32 = softplus(W_dt^T @ dt^T + b_dt[row])
  gemm_bf16<1, 0><<<dim3(L_SEQ / 128, DI / 128), 256, 0, stream>>>(
      Wdt_t, DTR, xdbl, 128, deltaT, L_SEQ, DI, L_SEQ, DTR, b_dt, nullptr, 0);

  trans_bf16<<<dim3(DM / 64, DI / 64), 256, 0, stream>>>(W_out, Wtout, DI, DM);

  scan_pass1<<<dim3(DI / 4, NSEG), 64, 0, stream>>>(
      deltaT, u2T, xdbl, A_log, hend, aprod);

  scan_pass3<<<dim3(DI / 4, NSEG), 64, 0, stream>>>(
      deltaT, u2T, resT, xdbl, A_log, Dp, hend, aprod, ybT);

  transpose_b16<<<dim3(L_SEQ / 64, DI / 64), 256, 0, stream>>>(ybT, yb, DI, L_SEQ);

  gemm_bf16<2, 0><<<dim3(DM / 128, L_SEQ / 128), 256, 0, stream>>>(
      yb, DI, Wtout, DI, d_out, DM, L_SEQ, DM, DI, nullptr, x, DM);
}

// Round 7
// 188.969 us; speedup vs baseline: 2.1367x; 1.6545x over previous
//
#include <hip/hip_runtime.h>
#include <math.h>

#define L_SEQ 2048
#define DM 1024
#define DI 2048
#define DS 16
#define DTR 64
#define EPS 1e-5f
#define NSEG 16
#define SEGLEN 128

typedef float f32x4 __attribute__((ext_vector_type(4)));
typedef __bf16 bf16x8 __attribute__((ext_vector_type(8)));
typedef _Float16 h16x4 __attribute__((ext_vector_type(4)));

static __device__ __forceinline__ unsigned short f2bf(float f) {
  union { float f; unsigned u; } v; v.f = f;
  unsigned r = v.u + 0x7fffu + ((v.u >> 16) & 1u);
  return (unsigned short)(r >> 16);
}
static __device__ __forceinline__ float bf2f(unsigned short s) {
  union { unsigned u; float f; } v; v.u = ((unsigned)s) << 16;
  return v.f;
}

// global -> LDS direct copy, 16B per lane. LDS dest is wave-uniform base;
// HW writes lane l at base + l*16. Integer round-trip casts (CK pattern):
// generic LDS pointer low 32 bits == LDS offset on gfx9xx.
static __device__ __forceinline__ void gload16(const void* g, void* l) {
  __builtin_amdgcn_global_load_lds(
      (__attribute__((address_space(1))) void*)(unsigned long long)(g),
      (__attribute__((address_space(3))) void*)(unsigned)(unsigned long long)(l),
      16, 0, 0);
}

// ---------------- LayerNorm -> bf16 ----------------
__global__ __launch_bounds__(256) void ln_kernel(const float* __restrict__ x,
                                                 const float* __restrict__ sc,
                                                 const float* __restrict__ bi,
                                                 unsigned short* __restrict__ xnb) {
  int row = blockIdx.x;
  int t = threadIdx.x;
  float4 xv = ((const float4*)(x + (size_t)row * DM))[t];
  float s  = xv.x + xv.y + xv.z + xv.w;
  float s2 = xv.x*xv.x + xv.y*xv.y + xv.z*xv.z + xv.w*xv.w;
  #pragma unroll
  for (int m = 32; m >= 1; m >>= 1) {
    s  += __shfl_xor(s, m);
    s2 += __shfl_xor(s2, m);
  }
  __shared__ float red[8];
  int wid = t >> 6, lane = t & 63;
  if (lane == 0) { red[wid] = s; red[4 + wid] = s2; }
  __syncthreads();
  s  = red[0] + red[1] + red[2] + red[3];
  s2 = red[4] + red[5] + red[6] + red[7];
  float mu = s * (1.f / DM);
  float var = s2 * (1.f / DM) - mu * mu;
  float rs = rsqrtf(var + EPS);
  float4 sc4 = ((const float4*)sc)[t];
  float4 bi4 = ((const float4*)bi)[t];
  ushort4 ob;
  ob.x = f2bf((xv.x - mu) * rs * sc4.x + bi4.x);
  ob.y = f2bf((xv.y - mu) * rs * sc4.y + bi4.y);
  ob.z = f2bf((xv.z - mu) * rs * sc4.z + bi4.z);
  ob.w = f2bf((xv.w - mu) * rs * sc4.w + bi4.w);
  *(ushort4*)&xnb[(size_t)row * DM + t * 4] = ob;
}

// ---------------- transpose + fp32->bf16: W[K][N] -> Wt[N][K] (64-mult dims) ----------------
__global__ __launch_bounds__(256) void trans_bf16(
    const float* __restrict__ W, unsigned short* __restrict__ Wt, int K, int N)
{
  __shared__ unsigned short s[64][80];
  int n0 = blockIdx.x * 64, k0 = blockIdx.y * 64;
  int tid = threadIdx.x;
  #pragma unroll
  for (int p = 0; p < 4; ++p) {
    int i = p * 16 + (tid >> 4);
    int j = (tid & 15) * 4;
    float4 w = *(const float4*)&W[(size_t)(k0 + i) * N + n0 + j];
    s[j + 0][i] = f2bf(w.x); s[j + 1][i] = f2bf(w.y);
    s[j + 2][i] = f2bf(w.z); s[j + 3][i] = f2bf(w.w);
  }
  __syncthreads();
  #pragma unroll
  for (int q = 0; q < 2; ++q) {
    int n = q * 32 + (tid >> 3);
    int i8 = (tid & 7) * 8;
    *(int4*)&Wt[(size_t)(n0 + n) * K + k0 + i8] = *(const int4*)&s[n][i8];
  }
}

// ---------------- bf16 [R][C] -> bf16 [C][R] tile transpose ----------------
__global__ __launch_bounds__(256) void transpose_b16(
    const unsigned short* __restrict__ in, unsigned short* __restrict__ out,
    int R, int C)
{
  __shared__ unsigned short s[64][72];
  int c0 = blockIdx.x * 64, r0 = blockIdx.y * 64;
  int tid = threadIdx.x;
  #pragma unroll
  for (int p = 0; p < 2; ++p) {
    int r = p * 32 + (tid >> 3);
    int c = (tid & 7) * 8;
    *(int4*)&s[r][c] = *(const int4*)&in[(size_t)(r0 + r) * C + c0 + c];
  }
  __syncthreads();
  #pragma unroll
  for (int p = 0; p < 2; ++p) {
    int c = p * 32 + (tid >> 3);
    int r = (tid & 7) * 8;
    ushort4 a, b;
    a.x = s[r + 0][c]; a.y = s[r + 1][c]; a.z = s[r + 2][c]; a.w = s[r + 3][c];
    b.x = s[r + 4][c]; b.y = s[r + 5][c]; b.z = s[r + 6][c]; b.w = s[r + 7][c];
    *(ushort4*)&out[(size_t)(c0 + c) * R + r0 + r] = a;
    *(ushort4*)&out[(size_t)(c0 + c) * R + r0 + r + 4] = b;
  }
}

// ---------------- W_x[2048][96] fp32 -> Wxt[128][2048] bf16 (zero-padded rows) ----------------
__global__ __launch_bounds__(256) void trans_wx(
    const float* __restrict__ Wx, unsigned short* __restrict__ Wxt)
{
  int i = blockIdx.x * 256 + threadIdx.x;   // over 128*2048
  int n = i >> 11, k = i & 2047;
  Wxt[i] = (n < 96) ? f2bf(Wx[(size_t)k * 96 + n]) : (unsigned short)0;
}

// ---------------- bf16 MFMA GEMM v2: C = A(MxK) @ Bt(NxK)^T ----------------
// BK=64, 4 waves (2x2), global_load_lds staging (m97 structure: stage ->
// barrier -> ds_read+MFMA -> barrier), linear LDS, XCD-swizzled blockIdx.
// SPLITK via gridDim.z: fp32 partials at Cv + z*M*ldc (OUTB must be 0).
// EPI: 0 none, 1 softplus(acc + bias[ROW]).  OUTB: 0 fp32, 1 bf16.
template<int BM, int BN, int EPI, int OUTB, int SPLITK>
__global__ __launch_bounds__(256) void gemm2(
    const unsigned short* __restrict__ A, int lda,
    const unsigned short* __restrict__ Bt, int ldb,
    void* __restrict__ Cv, int ldc,
    int M, int N, int K,
    const float* __restrict__ bias)
{
  constexpr int WM = BM / 2, WN = BN / 2;
  constexpr int FM = WM / 16, FN = WN / 16;
  __shared__ __align__(16) unsigned short smA[BM * 64];
  __shared__ __align__(16) unsigned short smB[BN * 64];

  // bijective XCD swizzle over x*y (grids are multiples of 8)
  int nwg = gridDim.x * gridDim.y;
  int bid = blockIdx.y * gridDim.x + blockIdx.x;
  if ((nwg & 7) == 0) {
    int cpx = nwg >> 3;
    bid = (bid & 7) * cpx + (bid >> 3);
  }
  int bx = bid % gridDim.x;
  int by = bid / gridDim.x;
  int m0 = by * BM, n0 = bx * BN;

  int tid = threadIdx.x;
  int lane = tid & 63, wid = tid >> 6;
  int wm = wid >> 1, wn = wid & 1;

  int kb = blockIdx.z * (K / SPLITK);
  int nt = (K / SPLITK) / 64;

  int rs = lane >> 3;          // row within an 8-row chunk
  int cs = (lane & 7) * 8;     // ushort col within BK=64

  f32x4 acc[FM][FN];
  #pragma unroll
  for (int m = 0; m < FM; ++m)
    #pragma unroll
    for (int n = 0; n < FN; ++n) acc[m][n] = (f32x4){0.f, 0.f, 0.f, 0.f};

  for (int kt = 0; kt < nt; ++kt) {
    __syncthreads();   // all waves done reading previous tile
    #pragma unroll
    for (int i = 0; i < BM / 32; ++i) {
      int chunk = wid * (BM / 32) + i;   // 8 rows x 128B per chunk
      gload16(A + (size_t)(m0 + chunk * 8 + rs) * lda + kb + kt * 64 + cs,
              (char*)smA + chunk * 1024);
    }
    #pragma unroll
    for (int i = 0; i < BN / 32; ++i) {
      int chunk = wid * (BN / 32) + i;
      gload16(Bt + (size_t)(n0 + chunk * 8 + rs) * ldb + kb + kt * 64 + cs,
              (char*)smB + chunk * 1024);
    }
    __syncthreads();   // compiler drains vmcnt(0) before s_barrier

    #pragma unroll
    for (int kk = 0; kk < 2; ++kk) {
      bf16x8 aF[FM], bF[FN];
      #pragma unroll
      for (int m = 0; m < FM; ++m) {
        int r = wm * WM + m * 16 + (lane & 15);
        aF[m] = *(const bf16x8*)((const char*)smA + r * 128 + kk * 64 + (lane >> 4) * 16);
      }
      #pragma unroll
      for (int n = 0; n < FN; ++n) {
        int r = wn * WN + n * 16 + (lane & 15);
        bF[n] = *(const bf16x8*)((const char*)smB + r * 128 + kk * 64 + (lane >> 4) * 16);
      }
      #pragma unroll
      for (int m = 0; m < FM; ++m)
        #pragma unroll
        for (int n = 0; n < FN; ++n)
          acc[m][n] = __builtin_amdgcn_mfma_f32_16x16x32_bf16(
              aF[m], bF[n], acc[m][n], 0, 0, 0);
    }
  }

  float* Cf = (float*)Cv + (size_t)blockIdx.z * M * ldc;
  unsigned short* Cb = (unsigned short*)Cv;
  int cm = (lane >> 4) * 4, cn = lane & 15;
  #pragma unroll
  for (int m = 0; m < FM; ++m)
    #pragma unroll
    for (int n = 0; n < FN; ++n) {
      int col = n0 + wn * WN + n * 16 + cn;
      #pragma unroll
      for (int r = 0; r < 4; ++r) {
        int row = m0 + wm * WM + m * 16 + cm + r;
        float v = acc[m][n][r];
        if (EPI == 1) {
          float w = v + bias[row];
          v = (w > 20.f) ? w : log1pf(__expf(w));
        }
        if (OUTB) Cb[(size_t)row * ldc + col] = f2bf(v);
        else      Cf[(size_t)row * ldc + col] = v;
      }
    }
}

// ---------------- split-K reduce: part[16][2048*128] fp32 -> xdbl bf16 ----------------
__global__ __launch_bounds__(256) void xdbl_reduce(
    const float* __restrict__ part, unsigned short* __restrict__ xdbl)
{
  int i = (blockIdx.x * 256 + threadIdx.x) * 4;   // over 2048*128
  const int SL = 2048 * 128;
  float4 s = *(const float4*)&part[i];
  #pragma unroll
  for (int z = 1; z < 16; ++z) {
    float4 p = *(const float4*)&part[(size_t)z * SL + i];
    s.x += p.x; s.y += p.y; s.z += p.z; s.w += p.w;
  }
  ushort4 ob;
  ob.x = f2bf(s.x); ob.y = f2bf(s.y); ob.z = f2bf(s.z); ob.w = f2bf(s.w);
  *(ushort4*)&xdbl[i] = ob;
}

// ---------------- final split-K reduce + residual: d_out = p0 + p1 + x ----------------
__global__ __launch_bounds__(256) void out_reduce(
    const float* __restrict__ part, const float* __restrict__ x,
    float* __restrict__ out)
{
  int i = (blockIdx.x * 256 + threadIdx.x) * 4;   // over 2048*1024
  const int SL = 2048 * 1024;
  float4 a = *(const float4*)&part[i];
  float4 b = *(const float4*)&part[SL + i];
  float4 r = *(const float4*)&x[i];
  float4 o;
  o.x = a.x + b.x + r.x; o.y = a.y + b.y + r.y;
  o.z = a.z + b.z + r.z; o.w = a.w + b.w + r.w;
  *(float4*)&out[i] = o;
}

// ---------------- causal conv4 + SiLU on transposed layout ----------------
__global__ __launch_bounds__(256) void conv_silu_kernel(
    const unsigned short* __restrict__ xrT,
    const float* __restrict__ Wc, const float* __restrict__ bc,
    unsigned short* __restrict__ u2T)
{
  int d = blockIdx.x;
  int l0 = blockIdx.y * 1024 + threadIdx.x * 4;
  const unsigned short* ur = xrT + (size_t)d * L_SEQ;
  float w0 = Wc[0 * DI + d], w1 = Wc[1 * DI + d];
  float w2 = Wc[2 * DI + d], w3 = Wc[3 * DI + d];
  float b = bc[d];
  ushort4 v0 = *(const ushort4*)&ur[l0];
  ushort4 vm; vm.x = vm.y = vm.z = vm.w = 0;
  if (l0 > 0) vm = *(const ushort4*)&ur[l0 - 4];
  float um3 = bf2f(vm.y), um2 = bf2f(vm.z), um1 = bf2f(vm.w);
  float x0 = bf2f(v0.x), x1 = bf2f(v0.y), x2 = bf2f(v0.z), x3 = bf2f(v0.w);
  float y0 = b + w0 * um3 + w1 * um2 + w2 * um1 + w3 * x0;
  float y1 = b + w0 * um2 + w1 * um1 + w2 * x0  + w3 * x1;
  float y2 = b + w0 * um1 + w1 * x0  + w2 * x1  + w3 * x2;
  float y3 = b + w0 * x0  + w1 * x1  + w2 * x2  + w3 * x3;
  ushort4 ob;
  ob.x = f2bf(y0 / (1.f + __expf(-y0)));
  ob.y = f2bf(y1 / (1.f + __expf(-y1)));
  ob.z = f2bf(y2 / (1.f + __expf(-y2)));
  ob.w = f2bf(y3 / (1.f + __expf(-y3)));
  *(ushort4*)&u2T[(size_t)d * L_SEQ + l0] = ob;
}

// ================= segmented selective scan (bf16 delta) =================

// ---- pass 1: segment summaries (prod dA, h_end | h0=0) ----
__global__ __launch_bounds__(64) void scan_pass1(
    const unsigned short* __restrict__ deltaT, const unsigned short* __restrict__ u2T,
    const unsigned short* __restrict__ xdbl,
    const float* __restrict__ A_log,
    float* __restrict__ hend, float* __restrict__ aprod)
{
  int t = threadIdx.x;
  int ch = t >> 4, n = t & 15;
  int li = (t & 15) * 4;
  int d0 = blockIdx.x * 4, d = d0 + ch;
  int s = blockIdx.y;
  int base = s * SEGLEN;

  __shared__ __align__(16) float sdT[4][68], suT[4][68], sBT[16][68];

  float An = -__expf(A_log[d * DS + n]);
  float h = 0.f, P = 1.f;

  ushort4 rdu, ru, rB[4];
  auto LOAD = [&](int c0) {
    rdu = *(const ushort4*)&deltaT[(size_t)d * L_SEQ + c0 + li];
    ru  = *(const ushort4*)&u2T[(size_t)d * L_SEQ + c0 + li];
    #pragma unroll
    for (int r = 0; r < 4; ++r) {
      int ll = c0 + (t >> 2) + r * 16;
      rB[r] = *(const ushort4*)&xdbl[(size_t)ll * 128 + 64 + (t & 3) * 4];
    }
  };

  LOAD(base);
  for (int cc = 0; cc < 2; ++cc) {
    __syncthreads();
    sdT[ch][li + 0] = bf2f(rdu.x); sdT[ch][li + 1] = bf2f(rdu.y);
    sdT[ch][li + 2] = bf2f(rdu.z); sdT[ch][li + 3] = bf2f(rdu.w);
    suT[ch][li + 0] = bf2f(ru.x);  suT[ch][li + 1] = bf2f(ru.y);
    suT[ch][li + 2] = bf2f(ru.z);  suT[ch][li + 3] = bf2f(ru.w);
    #pragma unroll
    for (int r = 0; r < 4; ++r) {
      int ll = (t >> 2) + r * 16;
      int nb = (t & 3) * 4;
      sBT[nb + 0][ll] = bf2f(rB[r].x); sBT[nb + 1][ll] = bf2f(rB[r].y);
      sBT[nb + 2][ll] = bf2f(rB[r].z); sBT[nb + 3][ll] = bf2f(rB[r].w);
    }
    if (cc == 0) LOAD(base + 64);
    __syncthreads();

    #pragma unroll
    for (int g = 0; g < 64; g += 4) {
      float4 dl4 = *(const float4*)&sdT[ch][g];
      float4 ul4 = *(const float4*)&suT[ch][g];
      float4 Bn4 = *(const float4*)&sBT[n][g];
      float dl[4] = {dl4.x, dl4.y, dl4.z, dl4.w};
      float ul[4] = {ul4.x, ul4.y, ul4.z, ul4.w};
      float Bn[4] = {Bn4.x, Bn4.y, Bn4.z, Bn4.w};
      #pragma unroll
      for (int i = 0; i < 4; ++i) {
        float dA = __expf(dl[i] * An);
        P *= dA;
        h = dA * h + (dl[i] * ul[i]) * Bn[i];
      }
    }
  }
  size_t idx = (size_t)s * (DI * DS) + d0 * DS + t;
  hend[idx]  = h;
  aprod[idx] = P;
}

// ---- pass 3: full scan per segment with stitched h_in ----
__global__ __launch_bounds__(64) void scan_pass3(
    const unsigned short* __restrict__ deltaT, const unsigned short* __restrict__ u2T,
    const unsigned short* __restrict__ resT,
    const unsigned short* __restrict__ xdbl,
    const float* __restrict__ A_log, const float* __restrict__ Dp,
    const float* __restrict__ hend, const float* __restrict__ aprod,
    unsigned short* __restrict__ ybT)
{
  int t = threadIdx.x;
  int ch = t >> 4, n = t & 15;
  int li = (t & 15) * 4;
  int d0 = blockIdx.x * 4, d = d0 + ch;
  int s = blockIdx.y;
  int base = s * SEGLEN;

  __shared__ __align__(16) float sdT[4][68], suT[4][68];
  __shared__ __align__(16) float sBT[16][68], sCT[16][68];
  __shared__ __align__(16) _Float16 svh[64][68];

  float An = -__expf(A_log[d * DS + n]);
  float Dd = Dp[d];

  float h = 0.f;
  int fi = d0 * DS + t;
  for (int k = 0; k < s; ++k)
    h = aprod[(size_t)k * (DI * DS) + fi] * h + hend[(size_t)k * (DI * DS) + fi];

  ushort4 rdu, ru, rB[4], rC[4];
  auto LOAD = [&](int c0) {
    rdu = *(const ushort4*)&deltaT[(size_t)d * L_SEQ + c0 + li];
    ru  = *(const ushort4*)&u2T[(size_t)d * L_SEQ + c0 + li];
    #pragma unroll
    for (int r = 0; r < 4; ++r) {
      int ll = c0 + (t >> 2) + r * 16;
      int n4 = (t & 3) * 4;
      rB[r] = *(const ushort4*)&xdbl[(size_t)ll * 128 + 64 + n4];
      rC[r] = *(const ushort4*)&xdbl[(size_t)ll * 128 + 80 + n4];
    }
  };

  LOAD(base);
  for (int cc = 0; cc < 2; ++cc) {
    int c0 = base + cc * 64;
    __syncthreads();
    sdT[ch][li + 0] = bf2f(rdu.x); sdT[ch][li + 1] = bf2f(rdu.y);
    sdT[ch][li + 2] = bf2f(rdu.z); sdT[ch][li + 3] = bf2f(rdu.w);
    suT[ch][li + 0] = bf2f(ru.x);  suT[ch][li + 1] = bf2f(ru.y);
    suT[ch][li + 2] = bf2f(ru.z);  suT[ch][li + 3] = bf2f(ru.w);
    #pragma unroll
    for (int r = 0; r < 4; ++r) {
      int ll = (t >> 2) + r * 16;
      int nb = (t & 3) * 4;
      sBT[nb + 0][ll] = bf2f(rB[r].x); sBT[nb + 1][ll] = bf2f(rB[r].y);
      sBT[nb + 2][ll] = bf2f(rB[r].z); sBT[nb + 3][ll] = bf2f(rB[r].w);
      sCT[nb + 0][ll] = bf2f(rC[r].x); sCT[nb + 1][ll] = bf2f(rC[r].y);
      sCT[nb + 2][ll] = bf2f(rC[r].z); sCT[nb + 3][ll] = bf2f(rC[r].w);
    }
    if (cc == 0) LOAD(base + 64);
    __syncthreads();

    #pragma unroll
    for (int g = 0; g < 64; g += 4) {
      float4 dl4 = *(const float4*)&sdT[ch][g];
      float4 ul4 = *(const float4*)&suT[ch][g];
      float4 Bn4 = *(const float4*)&sBT[n][g];
      float4 Cn4 = *(const float4*)&sCT[n][g];
      float dl[4] = {dl4.x, dl4.y, dl4.z, dl4.w};
      float ul[4] = {ul4.x, ul4.y, ul4.z, ul4.w};
      float Bn[4] = {Bn4.x, Bn4.y, Bn4.z, Bn4.w};
      float Cn[4] = {Cn4.x, Cn4.y, Cn4.z, Cn4.w};
      #pragma unroll
      for (int i = 0; i < 4; ++i) {
        float dA = __expf(dl[i] * An);
        h = dA * h + (dl[i] * ul[i]) * Bn[i];
        float vv = h * Cn[i];
        if (n == 0) vv += ul[i] * Dd;
        svh[g + i][t] = (_Float16)vv;
      }
    }
    __syncthreads();

    #pragma unroll
    for (int r = 0; r < 4; ++r) {
      int ll = (t >> 2) + r * 16;
      int c2 = t & 3;
      const h16x4* p = (const h16x4*)&svh[ll][c2 * 16];
      h16x4 a = p[0], b = p[1], c = p[2], e = p[3];
      float sA = ((float)a.x + (float)a.y) + ((float)a.z + (float)a.w);
      float sB = ((float)b.x + (float)b.y) + ((float)b.z + (float)b.w);
      float sC = ((float)c.x + (float)c.y) + ((float)c.z + (float)c.w);
      float sE = ((float)e.x + (float)e.y) + ((float)e.z + (float)e.w);
      float sum = (sA + sB) + (sC + sE);
      float rv = bf2f(resT[(size_t)(d0 + c2) * L_SEQ + c0 + ll]);
      float sig = 1.f / (1.f + __expf(-rv));
      ybT[(size_t)(d0 + c2) * L_SEQ + c0 + ll] = f2bf(sum * rv * sig);
    }
  }
}

// ---------------- launch ----------------
extern "C" void kernel_launch(void* const* d_in, const int* in_sizes, int n_in,
                              void* d_out, int out_size, void* d_ws, size_t ws_size,
                              hipStream_t stream)
{
  const float* x      = (const float*)d_in[0];
  const float* W_in   = (const float*)d_in[1];
  const float* W_conv = (const float*)d_in[2];
  const float* b_conv = (const float*)d_in[3];
  const float* W_x    = (const float*)d_in[4];
  const float* W_dt   = (const float*)d_in[5];
  const float* b_dt   = (const float*)d_in[6];
  const float* A_log  = (const float*)d_in[7];
  const float* Dp     = (const float*)d_in[8];
  const float* W_out  = (const float*)d_in[9];
  const float* ln_s   = (const float*)d_in[10];
  const float* ln_b   = (const float*)d_in[11];

  char* ws = (char*)d_ws;
  const size_t MB = 1u << 20;
  unsigned short* xnb    = (unsigned short*)(ws);               // 0-4 MB
  unsigned short* xrT    = (unsigned short*)(ws + 4 * MB);      // 4-20: bf16 [4096][2048]
  unsigned short* u2T    = (unsigned short*)(ws + 20 * MB);     // 20-28
  unsigned short* u2b    = (unsigned short*)(ws + 28 * MB);     // 28-36 (dead after xdbl gemm)
  float*          hend   = (float*)(ws + 28 * MB);              // 2 MB, aliases u2b
  float*          aprod  = (float*)(ws + 30 * MB);              // 2 MB, aliases u2b
  unsigned short* xdbl   = (unsigned short*)(ws + 36 * MB);     // 0.5 MB
  unsigned short* Wxt    = (unsigned short*)(ws + 36 * MB + 512 * 1024); // 0.5 MB
  unsigned short* Wdt_t  = (unsigned short*)(ws + 37 * MB);     // 0.25 MB
  unsigned short* deltaTb= (unsigned short*)(ws + 38 * MB);     // 38-46: bf16 [2048][2048]
  unsigned short* Wtin   = (unsigned short*)(ws + 38 * MB);     // aliases deltaTb (dead after GEMM1)
  float*          part   = (float*)(ws + 46 * MB);              // 46-62: split-K partials
  unsigned short* ybT    = (unsigned short*)(ws + 54 * MB);     // 54-62 (xdbl part dead; dead before final part)
  unsigned short* yb     = (unsigned short*)(ws + 4 * MB);      // aliases dead uT rows of xrT
  unsigned short* Wtout  = xnb;                                 // aliases xnb (dead after GEMM1)
  const unsigned short* resT = xrT + (size_t)DI * L_SEQ;        // rows [2048,4096)

  ln_kernel<<<L_SEQ, 256, 0, stream>>>(x, ln_s, ln_b, xnb);

  trans_bf16<<<dim3((2 * DI) / 64, DM / 64), 256, 0, stream>>>(W_in, Wtin, DM, 2 * DI);

  // xr^T [4096][2048] = (xn @ W_in)^T : A=Wtin[4096][1024], Bt=xnb[2048][1024]
  gemm2<64, 128, 0, 1, 1><<<dim3(L_SEQ / 128, (2 * DI) / 64), 256, 0, stream>>>(
      Wtin, DM, xnb, DM, xrT, L_SEQ, 2 * DI, L_SEQ, DM, nullptr);

  conv_silu_kernel<<<dim3(DI, 2), 256, 0, stream>>>(xrT, W_conv, b_conv, u2T);

  transpose_b16<<<dim3(L_SEQ / 64, DI / 64), 256, 0, stream>>>(u2T, u2b, DI, L_SEQ);

  trans_wx<<<(128 * 2048) / 256, 256, 0, stream>>>(W_x, Wxt);

  // x_dbl partials: A=u2b[2048][2048], Bt=Wxt[128][2048], split-K x16
  gemm2<64, 128, 0, 0, 16><<<dim3(1, L_SEQ / 64, 16), 256, 0, stream>>>(
      u2b, DI, Wxt, DI, part, 128, L_SEQ, 128, DI, nullptr);

  xdbl_reduce<<<(L_SEQ * 128) / 1024, 256, 0, stream>>>(part, xdbl);

  trans_bf16<<<dim3(DI / 64, DTR / 64), 256, 0, stream>>>(W_dt, Wdt_t, DTR, DI);

  // delta^T bf16 [2048][2048] = softplus(Wdt^T @ dt^T + b_dt[row])
  gemm2<64, 128, 1, 1, 1><<<dim3(L_SEQ / 128, DI / 64), 256, 0, stream>>>(
      Wdt_t, DTR, xdbl, 128, deltaTb, L_SEQ, DI, L_SEQ, DTR, b_dt);

  trans_bf16<<<dim3(DM / 64, DI / 64), 256, 0, stream>>>(W_out, Wtout, DI, DM);

  scan_pass1<<<dim3(DI / 4, NSEG), 64, 0, stream>>>(
      deltaTb, u2T, xdbl, A_log, hend, aprod);

  scan_pass3<<<dim3(DI / 4, NSEG), 64, 0, stream>>>(
      deltaTb, u2T, resT, xdbl, A_log, Dp, hend, aprod, ybT);

  transpose_b16<<<dim3(L_SEQ / 64, DI / 64), 256, 0, stream>>>(ybT, yb, DI, L_SEQ);

  // final: out partials = y @ W_out, split-K x2 (A=yb[2048][2048], Bt=Wtout[1024][2048])
  gemm2<64, 64, 0, 0, 2><<<dim3(DM / 64, L_SEQ / 64, 2), 256, 0, stream>>>(
      yb, DI, Wtout, DI, part, DM, L_SEQ, DM, DI, nullptr);

  out_reduce<<<(L_SEQ * DM) / 1024, 256, 0, stream>>>(part, x, (float*)d_out);
}

// Round 8
// 185.187 us; speedup vs baseline: 2.1803x; 1.0204x over previous
//
#include <hip/hip_runtime.h>
#include <math.h>

#define L_SEQ 2048
#define DM 1024
#define DI 2048
#define DS 16
#define DTR 64
#define EPS 1e-5f
#define NSEG 16
#define SEGLEN 128

typedef float f32x4 __attribute__((ext_vector_type(4)));
typedef __bf16 bf16x8 __attribute__((ext_vector_type(8)));
typedef _Float16 h16x2 __attribute__((ext_vector_type(2)));

static __device__ __forceinline__ unsigned short f2bf(float f) {
  union { float f; unsigned u; } v; v.f = f;
  unsigned r = v.u + 0x7fffu + ((v.u >> 16) & 1u);
  return (unsigned short)(r >> 16);
}
static __device__ __forceinline__ float bf2f(unsigned short s) {
  union { unsigned u; float f; } v; v.u = ((unsigned)s) << 16;
  return v.f;
}

// global -> LDS direct copy, 16B per lane (wave-uniform LDS base).
static __device__ __forceinline__ void gload16(const void* g, void* l) {
  __builtin_amdgcn_global_load_lds(
      (__attribute__((address_space(1))) void*)(unsigned long long)(g),
      (__attribute__((address_space(3))) void*)(unsigned)(unsigned long long)(l),
      16, 0, 0);
}

// ---------------- LayerNorm -> bf16 ----------------
__global__ __launch_bounds__(256) void ln_kernel(const float* __restrict__ x,
                                                 const float* __restrict__ sc,
                                                 const float* __restrict__ bi,
                                                 unsigned short* __restrict__ xnb) {
  int row = blockIdx.x;
  int t = threadIdx.x;
  float4 xv = ((const float4*)(x + (size_t)row * DM))[t];
  float s  = xv.x + xv.y + xv.z + xv.w;
  float s2 = xv.x*xv.x + xv.y*xv.y + xv.z*xv.z + xv.w*xv.w;
  #pragma unroll
  for (int m = 32; m >= 1; m >>= 1) {
    s  += __shfl_xor(s, m);
    s2 += __shfl_xor(s2, m);
  }
  __shared__ float red[8];
  int wid = t >> 6, lane = t & 63;
  if (lane == 0) { red[wid] = s; red[4 + wid] = s2; }
  __syncthreads();
  s  = red[0] + red[1] + red[2] + red[3];
  s2 = red[4] + red[5] + red[6] + red[7];
  float mu = s * (1.f / DM);
  float var = s2 * (1.f / DM) - mu * mu;
  float rs = rsqrtf(var + EPS);
  float4 sc4 = ((const float4*)sc)[t];
  float4 bi4 = ((const float4*)bi)[t];
  ushort4 ob;
  ob.x = f2bf((xv.x - mu) * rs * sc4.x + bi4.x);
  ob.y = f2bf((xv.y - mu) * rs * sc4.y + bi4.y);
  ob.z = f2bf((xv.z - mu) * rs * sc4.z + bi4.z);
  ob.w = f2bf((xv.w - mu) * rs * sc4.w + bi4.w);
  *(ushort4*)&xnb[(size_t)row * DM + t * 4] = ob;
}

// ---------------- transpose + fp32->bf16: W[K][N] -> Wt[N][K] (64-mult dims) ----------------
__global__ __launch_bounds__(256) void trans_bf16(
    const float* __restrict__ W, unsigned short* __restrict__ Wt, int K, int N)
{
  __shared__ unsigned short s[64][80];
  int n0 = blockIdx.x * 64, k0 = blockIdx.y * 64;
  int tid = threadIdx.x;
  #pragma unroll
  for (int p = 0; p < 4; ++p) {
    int i = p * 16 + (tid >> 4);
    int j = (tid & 15) * 4;
    float4 w = *(const float4*)&W[(size_t)(k0 + i) * N + n0 + j];
    s[j + 0][i] = f2bf(w.x); s[j + 1][i] = f2bf(w.y);
    s[j + 2][i] = f2bf(w.z); s[j + 3][i] = f2bf(w.w);
  }
  __syncthreads();
  #pragma unroll
  for (int q = 0; q < 2; ++q) {
    int n = q * 32 + (tid >> 3);
    int i8 = (tid & 7) * 8;
    *(int4*)&Wt[(size_t)(n0 + n) * K + k0 + i8] = *(const int4*)&s[n][i8];
  }
}

// ---------------- bf16 [R][C] -> bf16 [C][R] tile transpose ----------------
__global__ __launch_bounds__(256) void transpose_b16(
    const unsigned short* __restrict__ in, unsigned short* __restrict__ out,
    int R, int C)
{
  __shared__ unsigned short s[64][72];
  int c0 = blockIdx.x * 64, r0 = blockIdx.y * 64;
  int tid = threadIdx.x;
  #pragma unroll
  for (int p = 0; p < 2; ++p) {
    int r = p * 32 + (tid >> 3);
    int c = (tid & 7) * 8;
    *(int4*)&s[r][c] = *(const int4*)&in[(size_t)(r0 + r) * C + c0 + c];
  }
  __syncthreads();
  #pragma unroll
  for (int p = 0; p < 2; ++p) {
    int c = p * 32 + (tid >> 3);
    int r = (tid & 7) * 8;
    ushort4 a, b;
    a.x = s[r + 0][c]; a.y = s[r + 1][c]; a.z = s[r + 2][c]; a.w = s[r + 3][c];
    b.x = s[r + 4][c]; b.y = s[r + 5][c]; b.z = s[r + 6][c]; b.w = s[r + 7][c];
    *(ushort4*)&out[(size_t)(c0 + c) * R + r0 + r] = a;
    *(ushort4*)&out[(size_t)(c0 + c) * R + r0 + r + 4] = b;
  }
}

// ---------------- W_x[2048][96] fp32 -> Wxt[128][2048] bf16 (zero-padded rows) ----------------
__global__ __launch_bounds__(256) void trans_wx(
    const float* __restrict__ Wx, unsigned short* __restrict__ Wxt)
{
  int i = blockIdx.x * 256 + threadIdx.x;   // over 128*2048
  int n = i >> 11, k = i & 2047;
  Wxt[i] = (n < 96) ? f2bf(Wx[(size_t)k * 96 + n]) : (unsigned short)0;
}

// ---------------- bf16 MFMA GEMM v2: C = A(MxK) @ Bt(NxK)^T ----------------
template<int BM, int BN, int EPI, int OUTB, int SPLITK>
__global__ __launch_bounds__(256) void gemm2(
    const unsigned short* __restrict__ A, int lda,
    const unsigned short* __restrict__ Bt, int ldb,
    void* __restrict__ Cv, int ldc,
    int M, int N, int K,
    const float* __restrict__ bias)
{
  constexpr int WM = BM / 2, WN = BN / 2;
  constexpr int FM = WM / 16, FN = WN / 16;
  __shared__ __align__(16) unsigned short smA[BM * 64];
  __shared__ __align__(16) unsigned short smB[BN * 64];

  int nwg = gridDim.x * gridDim.y;
  int bid = blockIdx.y * gridDim.x + blockIdx.x;
  if ((nwg & 7) == 0) {
    int cpx = nwg >> 3;
    bid = (bid & 7) * cpx + (bid >> 3);
  }
  int bx = bid % gridDim.x;
  int by = bid / gridDim.x;
  int m0 = by * BM, n0 = bx * BN;

  int tid = threadIdx.x;
  int lane = tid & 63, wid = tid >> 6;
  int wm = wid >> 1, wn = wid & 1;

  int kb = blockIdx.z * (K / SPLITK);
  int nt = (K / SPLITK) / 64;

  int rs = lane >> 3;
  int cs = (lane & 7) * 8;

  f32x4 acc[FM][FN];
  #pragma unroll
  for (int m = 0; m < FM; ++m)
    #pragma unroll
    for (int n = 0; n < FN; ++n) acc[m][n] = (f32x4){0.f, 0.f, 0.f, 0.f};

  for (int kt = 0; kt < nt; ++kt) {
    __syncthreads();
    #pragma unroll
    for (int i = 0; i < BM / 32; ++i) {
      int chunk = wid * (BM / 32) + i;
      gload16(A + (size_t)(m0 + chunk * 8 + rs) * lda + kb + kt * 64 + cs,
              (char*)smA + chunk * 1024);
    }
    #pragma unroll
    for (int i = 0; i < BN / 32; ++i) {
      int chunk = wid * (BN / 32) + i;
      gload16(Bt + (size_t)(n0 + chunk * 8 + rs) * ldb + kb + kt * 64 + cs,
              (char*)smB + chunk * 1024);
    }
    __syncthreads();

    #pragma unroll
    for (int kk = 0; kk < 2; ++kk) {
      bf16x8 aF[FM], bF[FN];
      #pragma unroll
      for (int m = 0; m < FM; ++m) {
        int r = wm * WM + m * 16 + (lane & 15);
        aF[m] = *(const bf16x8*)((const char*)smA + r * 128 + kk * 64 + (lane >> 4) * 16);
      }
      #pragma unroll
      for (int n = 0; n < FN; ++n) {
        int r = wn * WN + n * 16 + (lane & 15);
        bF[n] = *(const bf16x8*)((const char*)smB + r * 128 + kk * 64 + (lane >> 4) * 16);
      }
      #pragma unroll
      for (int m = 0; m < FM; ++m)
        #pragma unroll
        for (int n = 0; n < FN; ++n)
          acc[m][n] = __builtin_amdgcn_mfma_f32_16x16x32_bf16(
              aF[m], bF[n], acc[m][n], 0, 0, 0);
    }
  }

  float* Cf = (float*)Cv + (size_t)blockIdx.z * M * ldc;
  unsigned short* Cb = (unsigned short*)Cv;
  int cm = (lane >> 4) * 4, cn = lane & 15;
  #pragma unroll
  for (int m = 0; m < FM; ++m)
    #pragma unroll
    for (int n = 0; n < FN; ++n) {
      int col = n0 + wn * WN + n * 16 + cn;
      #pragma unroll
      for (int r = 0; r < 4; ++r) {
        int row = m0 + wm * WM + m * 16 + cm + r;
        float v = acc[m][n][r];
        if (EPI == 1) {
          float w = v + bias[row];
          v = (w > 20.f) ? w : log1pf(__expf(w));
        }
        if (OUTB) Cb[(size_t)row * ldc + col] = f2bf(v);
        else      Cf[(size_t)row * ldc + col] = v;
      }
    }
}

// ---------------- split-K reduce: part[16][2048*128] fp32 -> xdbl bf16 ----------------
__global__ __launch_bounds__(256) void xdbl_reduce(
    const float* __restrict__ part, unsigned short* __restrict__ xdbl)
{
  int i = (blockIdx.x * 256 + threadIdx.x) * 4;
  const int SL = 2048 * 128;
  float4 s = *(const float4*)&part[i];
  #pragma unroll
  for (int z = 1; z < 16; ++z) {
    float4 p = *(const float4*)&part[(size_t)z * SL + i];
    s.x += p.x; s.y += p.y; s.z += p.z; s.w += p.w;
  }
  ushort4 ob;
  ob.x = f2bf(s.x); ob.y = f2bf(s.y); ob.z = f2bf(s.z); ob.w = f2bf(s.w);
  *(ushort4*)&xdbl[i] = ob;
}

// ---------------- final split-K reduce + residual ----------------
__global__ __launch_bounds__(256) void out_reduce(
    const float* __restrict__ part, const float* __restrict__ x,
    float* __restrict__ out)
{
  int i = (blockIdx.x * 256 + threadIdx.x) * 4;
  const int SL = 2048 * 1024;
  float4 a = *(const float4*)&part[i];
  float4 b = *(const float4*)&part[SL + i];
  float4 r = *(const float4*)&x[i];
  float4 o;
  o.x = a.x + b.x + r.x; o.y = a.y + b.y + r.y;
  o.z = a.z + b.z + r.z; o.w = a.w + b.w + r.w;
  *(float4*)&out[i] = o;
}

// ---------------- causal conv4 + SiLU on transposed layout ----------------
__global__ __launch_bounds__(256) void conv_silu_kernel(
    const unsigned short* __restrict__ xrT,
    const float* __restrict__ Wc, const float* __restrict__ bc,
    unsigned short* __restrict__ u2T)
{
  int d = blockIdx.x;
  int l0 = blockIdx.y * 1024 + threadIdx.x * 4;
  const unsigned short* ur = xrT + (size_t)d * L_SEQ;
  float w0 = Wc[0 * DI + d], w1 = Wc[1 * DI + d];
  float w2 = Wc[2 * DI + d], w3 = Wc[3 * DI + d];
  float b = bc[d];
  ushort4 v0 = *(const ushort4*)&ur[l0];
  ushort4 vm; vm.x = vm.y = vm.z = vm.w = 0;
  if (l0 > 0) vm = *(const ushort4*)&ur[l0 - 4];
  float um3 = bf2f(vm.y), um2 = bf2f(vm.z), um1 = bf2f(vm.w);
  float x0 = bf2f(v0.x), x1 = bf2f(v0.y), x2 = bf2f(v0.z), x3 = bf2f(v0.w);
  float y0 = b + w0 * um3 + w1 * um2 + w2 * um1 + w3 * x0;
  float y1 = b + w0 * um2 + w1 * um1 + w2 * x0  + w3 * x1;
  float y2 = b + w0 * um1 + w1 * x0  + w2 * x1  + w3 * x2;
  float y3 = b + w0 * x0  + w1 * x1  + w2 * x2  + w3 * x3;
  ushort4 ob;
  ob.x = f2bf(y0 / (1.f + __expf(-y0)));
  ob.y = f2bf(y1 / (1.f + __expf(-y1)));
  ob.z = f2bf(y2 / (1.f + __expf(-y2)));
  ob.w = f2bf(y3 / (1.f + __expf(-y3)));
  *(ushort4*)&u2T[(size_t)d * L_SEQ + l0] = ob;
}

// ================= segmented selective scan v2 =================
// 128 threads = 8 channels x 16 states; B/C staging shared across 8 ch.
// Staging pre-computes du = delta*u (shared over n); u*D and res-gate moved
// to the post-pass (u/res re-read from L2). svh row stride 134 fp16 = 67
// dwords (gcd(3,32)=1) -> conflict-free post-pass reads.

// ---- pass 1: segment summaries (prod dA, h_end | h0=0) ----
__global__ __launch_bounds__(128) void scan_pass1(
    const unsigned short* __restrict__ deltaT, const unsigned short* __restrict__ u2T,
    const unsigned short* __restrict__ xdbl,
    const float* __restrict__ A_log,
    float* __restrict__ hend, float* __restrict__ aprod)
{
  int t = threadIdx.x;
  int ch = t >> 4, n = t & 15;
  int li = (t & 15) * 4;
  int d0 = blockIdx.x * 8, d = d0 + ch;
  int s = blockIdx.y;
  int base = s * SEGLEN;

  __shared__ __align__(16) float sdT[8][68], suT[8][68], sBT[16][68];

  float An = -__expf(A_log[d * DS + n]);
  float h = 0.f, P = 1.f;

  ushort4 rdu, ru, rB[2];
  auto LOAD = [&](int c0) {
    rdu = *(const ushort4*)&deltaT[(size_t)d * L_SEQ + c0 + li];
    ru  = *(const ushort4*)&u2T[(size_t)d * L_SEQ + c0 + li];
    #pragma unroll
    for (int q = 0; q < 2; ++q) {
      int ll = c0 + (t >> 2) + q * 32;
      rB[q] = *(const ushort4*)&xdbl[(size_t)ll * 128 + 64 + (t & 3) * 4];
    }
  };

  LOAD(base);
  for (int cc = 0; cc < 2; ++cc) {
    __syncthreads();
    float d0v = bf2f(rdu.x), d1v = bf2f(rdu.y), d2v = bf2f(rdu.z), d3v = bf2f(rdu.w);
    sdT[ch][li + 0] = d0v; sdT[ch][li + 1] = d1v;
    sdT[ch][li + 2] = d2v; sdT[ch][li + 3] = d3v;
    suT[ch][li + 0] = d0v * bf2f(ru.x); suT[ch][li + 1] = d1v * bf2f(ru.y);
    suT[ch][li + 2] = d2v * bf2f(ru.z); suT[ch][li + 3] = d3v * bf2f(ru.w);
    #pragma unroll
    for (int q = 0; q < 2; ++q) {
      int ll = (t >> 2) + q * 32;
      int nb = (t & 3) * 4;
      sBT[nb + 0][ll] = bf2f(rB[q].x); sBT[nb + 1][ll] = bf2f(rB[q].y);
      sBT[nb + 2][ll] = bf2f(rB[q].z); sBT[nb + 3][ll] = bf2f(rB[q].w);
    }
    if (cc == 0) LOAD(base + 64);
    __syncthreads();

    #pragma unroll
    for (int g = 0; g < 64; g += 4) {
      float4 dl4 = *(const float4*)&sdT[ch][g];
      float4 du4 = *(const float4*)&suT[ch][g];
      float4 Bn4 = *(const float4*)&sBT[n][g];
      float dl[4] = {dl4.x, dl4.y, dl4.z, dl4.w};
      float du[4] = {du4.x, du4.y, du4.z, du4.w};
      float Bn[4] = {Bn4.x, Bn4.y, Bn4.z, Bn4.w};
      #pragma unroll
      for (int i = 0; i < 4; ++i) {
        float dA = __expf(dl[i] * An);
        P *= dA;
        h = dA * h + du[i] * Bn[i];
      }
    }
  }
  size_t idx = (size_t)s * (DI * DS) + d0 * DS + t;
  hend[idx]  = h;
  aprod[idx] = P;
}

// ---- pass 3: full scan per segment with stitched h_in ----
__global__ __launch_bounds__(128) void scan_pass3(
    const unsigned short* __restrict__ deltaT, const unsigned short* __restrict__ u2T,
    const unsigned short* __restrict__ resT,
    const unsigned short* __restrict__ xdbl,
    const float* __restrict__ A_log, const float* __restrict__ Dp,
    const float* __restrict__ hend, const float* __restrict__ aprod,
    unsigned short* __restrict__ ybT)
{
  int t = threadIdx.x;
  int ch = t >> 4, n = t & 15;
  int li = (t & 15) * 4;
  int d0 = blockIdx.x * 8, d = d0 + ch;
  int s = blockIdx.y;
  int base = s * SEGLEN;

  __shared__ __align__(16) float sdT[8][68], suT[8][68];
  __shared__ __align__(16) float sBT[16][68], sCT[16][68];
  __shared__ __align__(4) _Float16 svh[64][134];

  float An = -__expf(A_log[d * DS + n]);

  float h = 0.f;
  int fi = d0 * DS + t;
  for (int k = 0; k < s; ++k)
    h = aprod[(size_t)k * (DI * DS) + fi] * h + hend[(size_t)k * (DI * DS) + fi];

  ushort4 rdu, ru, rB[2], rC[2];
  auto LOAD = [&](int c0) {
    rdu = *(const ushort4*)&deltaT[(size_t)d * L_SEQ + c0 + li];
    ru  = *(const ushort4*)&u2T[(size_t)d * L_SEQ + c0 + li];
    #pragma unroll
    for (int q = 0; q < 2; ++q) {
      int ll = c0 + (t >> 2) + q * 32;
      int n4 = (t & 3) * 4;
      rB[q] = *(const ushort4*)&xdbl[(size_t)ll * 128 + 64 + n4];
      rC[q] = *(const ushort4*)&xdbl[(size_t)ll * 128 + 80 + n4];
    }
  };

  LOAD(base);
  for (int cc = 0; cc < 2; ++cc) {
    int c0 = base + cc * 64;
    __syncthreads();
    float d0v = bf2f(rdu.x), d1v = bf2f(rdu.y), d2v = bf2f(rdu.z), d3v = bf2f(rdu.w);
    sdT[ch][li + 0] = d0v; sdT[ch][li + 1] = d1v;
    sdT[ch][li + 2] = d2v; sdT[ch][li + 3] = d3v;
    suT[ch][li + 0] = d0v * bf2f(ru.x); suT[ch][li + 1] = d1v * bf2f(ru.y);
    suT[ch][li + 2] = d2v * bf2f(ru.z); suT[ch][li + 3] = d3v * bf2f(ru.w);
    #pragma unroll
    for (int q = 0; q < 2; ++q) {
      int ll = (t >> 2) + q * 32;
      int nb = (t & 3) * 4;
      sBT[nb + 0][ll] = bf2f(rB[q].x); sBT[nb + 1][ll] = bf2f(rB[q].y);
      sBT[nb + 2][ll] = bf2f(rB[q].z); sBT[nb + 3][ll] = bf2f(rB[q].w);
      sCT[nb + 0][ll] = bf2f(rC[q].x); sCT[nb + 1][ll] = bf2f(rC[q].y);
      sCT[nb + 2][ll] = bf2f(rC[q].z); sCT[nb + 3][ll] = bf2f(rC[q].w);
    }
    if (cc == 0) LOAD(base + 64);
    __syncthreads();

    #pragma unroll
    for (int g = 0; g < 64; g += 4) {
      float4 dl4 = *(const float4*)&sdT[ch][g];
      float4 du4 = *(const float4*)&suT[ch][g];
      float4 Bn4 = *(const float4*)&sBT[n][g];
      float4 Cn4 = *(const float4*)&sCT[n][g];
      float dl[4] = {dl4.x, dl4.y, dl4.z, dl4.w};
      float du[4] = {du4.x, du4.y, du4.z, du4.w};
      float Bn[4] = {Bn4.x, Bn4.y, Bn4.z, Bn4.w};
      float Cn[4] = {Cn4.x, Cn4.y, Cn4.z, Cn4.w};
      #pragma unroll
      for (int i = 0; i < 4; ++i) {
        float dA = __expf(dl[i] * An);
        h = dA * h + du[i] * Bn[i];
        svh[g + i][t] = (_Float16)(h * Cn[i]);
      }
    }
    __syncthreads();

    // post-pass: 16-state sum + u*D + res-gate; coalesced along l
    #pragma unroll
    for (int r = 0; r < 4; ++r) {
      int idx = r * 128 + t;
      int ll = idx & 63, c2 = idx >> 6;   // c2 = channel 0..7
      const _Float16* row = &svh[ll][c2 * 16];
      float sum = 0.f;
      #pragma unroll
      for (int k = 0; k < 8; ++k) {
        h16x2 pv = *(const h16x2*)&row[k * 2];
        sum += (float)pv.x + (float)pv.y;
      }
      int dd = d0 + c2;
      float uv = bf2f(u2T[(size_t)dd * L_SEQ + c0 + ll]);
      float rv = bf2f(resT[(size_t)dd * L_SEQ + c0 + ll]);
      float sig = 1.f / (1.f + __expf(-rv));
      float yv = (sum + uv * Dp[dd]) * rv * sig;
      ybT[(size_t)dd * L_SEQ + c0 + ll] = f2bf(yv);
    }
  }
}

// ---------------- launch ----------------
extern "C" void kernel_launch(void* const* d_in, const int* in_sizes, int n_in,
                              void* d_out, int out_size, void* d_ws, size_t ws_size,
                              hipStream_t stream)
{
  const float* x      = (const float*)d_in[0];
  const float* W_in   = (const float*)d_in[1];
  const float* W_conv = (const float*)d_in[2];
  const float* b_conv = (const float*)d_in[3];
  const float* W_x    = (const float*)d_in[4];
  const float* W_dt   = (const float*)d_in[5];
  const float* b_dt   = (const float*)d_in[6];
  const float* A_log  = (const float*)d_in[7];
  const float* Dp     = (const float*)d_in[8];
  const float* W_out  = (const float*)d_in[9];
  const float* ln_s   = (const float*)d_in[10];
  const float* ln_b   = (const float*)d_in[11];

  char* ws = (char*)d_ws;
  const size_t MB = 1u << 20;
  unsigned short* xnb    = (unsigned short*)(ws);               // 0-4 MB
  unsigned short* xrT    = (unsigned short*)(ws + 4 * MB);      // 4-20: bf16 [4096][2048]
  unsigned short* u2T    = (unsigned short*)(ws + 20 * MB);     // 20-28
  unsigned short* u2b    = (unsigned short*)(ws + 28 * MB);     // 28-36 (dead after xdbl gemm)
  float*          hend   = (float*)(ws + 28 * MB);              // 2 MB, aliases u2b
  float*          aprod  = (float*)(ws + 30 * MB);              // 2 MB, aliases u2b
  unsigned short* xdbl   = (unsigned short*)(ws + 36 * MB);     // 0.5 MB
  unsigned short* Wxt    = (unsigned short*)(ws + 36 * MB + 512 * 1024); // 0.5 MB
  unsigned short* Wdt_t  = (unsigned short*)(ws + 37 * MB);     // 0.25 MB
  unsigned short* deltaTb= (unsigned short*)(ws + 38 * MB);     // 38-46: bf16 [2048][2048]
  unsigned short* Wtin   = (unsigned short*)(ws + 38 * MB);     // aliases deltaTb (dead after GEMM1)
  float*          part   = (float*)(ws + 46 * MB);              // 46-62: split-K partials
  unsigned short* ybT    = (unsigned short*)(ws + 54 * MB);     // 54-62
  unsigned short* yb     = (unsigned short*)(ws + 4 * MB);      // aliases dead uT rows of xrT
  unsigned short* Wtout  = xnb;
  const unsigned short* resT = xrT + (size_t)DI * L_SEQ;        // rows [2048,4096)

  ln_kernel<<<L_SEQ, 256, 0, stream>>>(x, ln_s, ln_b, xnb);

  trans_bf16<<<dim3((2 * DI) / 64, DM / 64), 256, 0, stream>>>(W_in, Wtin, DM, 2 * DI);

  gemm2<64, 128, 0, 1, 1><<<dim3(L_SEQ / 128, (2 * DI) / 64), 256, 0, stream>>>(
      Wtin, DM, xnb, DM, xrT, L_SEQ, 2 * DI, L_SEQ, DM, nullptr);

  conv_silu_kernel<<<dim3(DI, 2), 256, 0, stream>>>(xrT, W_conv, b_conv, u2T);

  transpose_b16<<<dim3(L_SEQ / 64, DI / 64), 256, 0, stream>>>(u2T, u2b, DI, L_SEQ);

  trans_wx<<<(128 * 2048) / 256, 256, 0, stream>>>(W_x, Wxt);

  gemm2<64, 128, 0, 0, 16><<<dim3(1, L_SEQ / 64, 16), 256, 0, stream>>>(
      u2b, DI, Wxt, DI, part, 128, L_SEQ, 128, DI, nullptr);

  xdbl_reduce<<<(L_SEQ * 128) / 1024, 256, 0, stream>>>(part, xdbl);

  trans_bf16<<<dim3(DI / 64, DTR / 64), 256, 0, stream>>>(W_dt, Wdt_t, DTR, DI);

  gemm2<64, 128, 1, 1, 1><<<dim3(L_SEQ / 128, DI / 64), 256, 0, stream>>>(
      Wdt_t, DTR, xdbl, 128, deltaTb, L_SEQ, DI, L_SEQ, DTR, b_dt);

  trans_bf16<<<dim3(DM / 64, DI / 64), 256, 0, stream>>>(W_out, Wtout, DI, DM);

  // pass1 skips the last segment (its summary is never consumed)
  scan_pass1<<<dim3(DI / 8, NSEG - 1), 128, 0, stream>>>(
      deltaTb, u2T, xdbl, A_log, hend, aprod);

  scan_pass3<<<dim3(DI / 8, NSEG), 128, 0, stream>>>(
      deltaTb, u2T, resT, xdbl, A_log, Dp, hend, aprod, ybT);

  transpose_b16<<<dim3(L_SEQ / 64, DI / 64), 256, 0, stream>>>(ybT, yb, DI, L_SEQ);

  gemm2<64, 64, 0, 0, 2><<<dim3(DM / 64, L_SEQ / 64, 2), 256, 0, stream>>>(
      yb, DI, Wtout, DI, part, DM, L_SEQ, DM, DI, nullptr);

  out_reduce<<<(L_SEQ * DM) / 1024, 256, 0, stream>>>(part, x, (float*)d_out);
}

// Round 9
// 181.487 us; speedup vs baseline: 2.2248x; 1.0204x over previous
//
#include <hip/hip_runtime.h>
#include <math.h>

#define L_SEQ 2048
#define DM 1024
#define DI 2048
#define DS 16
#define DTR 64
#define EPS 1e-5f
#define NSEG 32
#define SEGLEN 64
#define NSTATE (DI * DS)

typedef float f32x4 __attribute__((ext_vector_type(4)));
typedef __bf16 bf16x8 __attribute__((ext_vector_type(8)));
typedef _Float16 h16x2 __attribute__((ext_vector_type(2)));

static __device__ __forceinline__ unsigned short f2bf(float f) {
  union { float f; unsigned u; } v; v.f = f;
  unsigned r = v.u + 0x7fffu + ((v.u >> 16) & 1u);
  return (unsigned short)(r >> 16);
}
static __device__ __forceinline__ float bf2f(unsigned short s) {
  union { unsigned u; float f; } v; v.u = ((unsigned)s) << 16;
  return v.f;
}

// global -> LDS direct copy, 16B per lane (wave-uniform LDS base).
static __device__ __forceinline__ void gload16(const void* g, void* l) {
  __builtin_amdgcn_global_load_lds(
      (__attribute__((address_space(1))) void*)(unsigned long long)(g),
      (__attribute__((address_space(3))) void*)(unsigned)(unsigned long long)(l),
      16, 0, 0);
}

// ---------------- LayerNorm -> bf16 ----------------
__global__ __launch_bounds__(256) void ln_kernel(const float* __restrict__ x,
                                                 const float* __restrict__ sc,
                                                 const float* __restrict__ bi,
                                                 unsigned short* __restrict__ xnb) {
  int row = blockIdx.x;
  int t = threadIdx.x;
  float4 xv = ((const float4*)(x + (size_t)row * DM))[t];
  float s  = xv.x + xv.y + xv.z + xv.w;
  float s2 = xv.x*xv.x + xv.y*xv.y + xv.z*xv.z + xv.w*xv.w;
  #pragma unroll
  for (int m = 32; m >= 1; m >>= 1) {
    s  += __shfl_xor(s, m);
    s2 += __shfl_xor(s2, m);
  }
  __shared__ float red[8];
  int wid = t >> 6, lane = t & 63;
  if (lane == 0) { red[wid] = s; red[4 + wid] = s2; }
  __syncthreads();
  s  = red[0] + red[1] + red[2] + red[3];
  s2 = red[4] + red[5] + red[6] + red[7];
  float mu = s * (1.f / DM);
  float var = s2 * (1.f / DM) - mu * mu;
  float rs = rsqrtf(var + EPS);
  float4 sc4 = ((const float4*)sc)[t];
  float4 bi4 = ((const float4*)bi)[t];
  ushort4 ob;
  ob.x = f2bf((xv.x - mu) * rs * sc4.x + bi4.x);
  ob.y = f2bf((xv.y - mu) * rs * sc4.y + bi4.y);
  ob.z = f2bf((xv.z - mu) * rs * sc4.z + bi4.z);
  ob.w = f2bf((xv.w - mu) * rs * sc4.w + bi4.w);
  *(ushort4*)&xnb[(size_t)row * DM + t * 4] = ob;
}

// ---------------- transpose + fp32->bf16: W[K][N] -> Wt[N][K] ----------------
__global__ __launch_bounds__(256) void trans_bf16(
    const float* __restrict__ W, unsigned short* __restrict__ Wt, int K, int N)
{
  __shared__ unsigned short s[64][80];
  int n0 = blockIdx.x * 64, k0 = blockIdx.y * 64;
  int tid = threadIdx.x;
  #pragma unroll
  for (int p = 0; p < 4; ++p) {
    int i = p * 16 + (tid >> 4);
    int j = (tid & 15) * 4;
    float4 w = *(const float4*)&W[(size_t)(k0 + i) * N + n0 + j];
    s[j + 0][i] = f2bf(w.x); s[j + 1][i] = f2bf(w.y);
    s[j + 2][i] = f2bf(w.z); s[j + 3][i] = f2bf(w.w);
  }
  __syncthreads();
  #pragma unroll
  for (int q = 0; q < 2; ++q) {
    int n = q * 32 + (tid >> 3);
    int i8 = (tid & 7) * 8;
    *(int4*)&Wt[(size_t)(n0 + n) * K + k0 + i8] = *(const int4*)&s[n][i8];
  }
}

// ---------------- bf16 [R][C] -> bf16 [C][R] tile transpose ----------------
__global__ __launch_bounds__(256) void transpose_b16(
    const unsigned short* __restrict__ in, unsigned short* __restrict__ out,
    int R, int C)
{
  __shared__ unsigned short s[64][72];
  int c0 = blockIdx.x * 64, r0 = blockIdx.y * 64;
  int tid = threadIdx.x;
  #pragma unroll
  for (int p = 0; p < 2; ++p) {
    int r = p * 32 + (tid >> 3);
    int c = (tid & 7) * 8;
    *(int4*)&s[r][c] = *(const int4*)&in[(size_t)(r0 + r) * C + c0 + c];
  }
  __syncthreads();
  #pragma unroll
  for (int p = 0; p < 2; ++p) {
    int c = p * 32 + (tid >> 3);
    int r = (tid & 7) * 8;
    ushort4 a, b;
    a.x = s[r + 0][c]; a.y = s[r + 1][c]; a.z = s[r + 2][c]; a.w = s[r + 3][c];
    b.x = s[r + 4][c]; b.y = s[r + 5][c]; b.z = s[r + 6][c]; b.w = s[r + 7][c];
    *(ushort4*)&out[(size_t)(c0 + c) * R + r0 + r] = a;
    *(ushort4*)&out[(size_t)(c0 + c) * R + r0 + r + 4] = b;
  }
}

// ---------------- W_x[2048][96] fp32 -> Wxt[128][2048] bf16 ----------------
__global__ __launch_bounds__(256) void trans_wx(
    const float* __restrict__ Wx, unsigned short* __restrict__ Wxt)
{
  int i = blockIdx.x * 256 + threadIdx.x;
  int n = i >> 11, k = i & 2047;
  Wxt[i] = (n < 96) ? f2bf(Wx[(size_t)k * 96 + n]) : (unsigned short)0;
}

// ---------------- bf16 MFMA GEMM v2 ----------------
template<int BM, int BN, int EPI, int OUTB, int SPLITK>
__global__ __launch_bounds__(256) void gemm2(
    const unsigned short* __restrict__ A, int lda,
    const unsigned short* __restrict__ Bt, int ldb,
    void* __restrict__ Cv, int ldc,
    int M, int N, int K,
    const float* __restrict__ bias)
{
  constexpr int WM = BM / 2, WN = BN / 2;
  constexpr int FM = WM / 16, FN = WN / 16;
  __shared__ __align__(16) unsigned short smA[BM * 64];
  __shared__ __align__(16) unsigned short smB[BN * 64];

  int nwg = gridDim.x * gridDim.y;
  int bid = blockIdx.y * gridDim.x + blockIdx.x;
  if ((nwg & 7) == 0) {
    int cpx = nwg >> 3;
    bid = (bid & 7) * cpx + (bid >> 3);
  }
  int bx = bid % gridDim.x;
  int by = bid / gridDim.x;
  int m0 = by * BM, n0 = bx * BN;

  int tid = threadIdx.x;
  int lane = tid & 63, wid = tid >> 6;
  int wm = wid >> 1, wn = wid & 1;

  int kb = blockIdx.z * (K / SPLITK);
  int nt = (K / SPLITK) / 64;

  int rs = lane >> 3;
  int cs = (lane & 7) * 8;

  f32x4 acc[FM][FN];
  #pragma unroll
  for (int m = 0; m < FM; ++m)
    #pragma unroll
    for (int n = 0; n < FN; ++n) acc[m][n] = (f32x4){0.f, 0.f, 0.f, 0.f};

  for (int kt = 0; kt < nt; ++kt) {
    __syncthreads();
    #pragma unroll
    for (int i = 0; i < BM / 32; ++i) {
      int chunk = wid * (BM / 32) + i;
      gload16(A + (size_t)(m0 + chunk * 8 + rs) * lda + kb + kt * 64 + cs,
              (char*)smA + chunk * 1024);
    }
    #pragma unroll
    for (int i = 0; i < BN / 32; ++i) {
      int chunk = wid * (BN / 32) + i;
      gload16(Bt + (size_t)(n0 + chunk * 8 + rs) * ldb + kb + kt * 64 + cs,
              (char*)smB + chunk * 1024);
    }
    __syncthreads();

    #pragma unroll
    for (int kk = 0; kk < 2; ++kk) {
      bf16x8 aF[FM], bF[FN];
      #pragma unroll
      for (int m = 0; m < FM; ++m) {
        int r = wm * WM + m * 16 + (lane & 15);
        aF[m] = *(const bf16x8*)((const char*)smA + r * 128 + kk * 64 + (lane >> 4) * 16);
      }
      #pragma unroll
      for (int n = 0; n < FN; ++n) {
        int r = wn * WN + n * 16 + (lane & 15);
        bF[n] = *(const bf16x8*)((const char*)smB + r * 128 + kk * 64 + (lane >> 4) * 16);
      }
      #pragma unroll
      for (int m = 0; m < FM; ++m)
        #pragma unroll
        for (int n = 0; n < FN; ++n)
          acc[m][n] = __builtin_amdgcn_mfma_f32_16x16x32_bf16(
              aF[m], bF[n], acc[m][n], 0, 0, 0);
    }
  }

  float* Cf = (float*)Cv + (size_t)blockIdx.z * M * ldc;
  unsigned short* Cb = (unsigned short*)Cv;
  int cm = (lane >> 4) * 4, cn = lane & 15;
  #pragma unroll
  for (int m = 0; m < FM; ++m)
    #pragma unroll
    for (int n = 0; n < FN; ++n) {
      int col = n0 + wn * WN + n * 16 + cn;
      #pragma unroll
      for (int r = 0; r < 4; ++r) {
        int row = m0 + wm * WM + m * 16 + cm + r;
        float v = acc[m][n][r];
        if (EPI == 1) {
          float w = v + bias[row];
          v = (w > 20.f) ? w : log1pf(__expf(w));
        }
        if (OUTB) Cb[(size_t)row * ldc + col] = f2bf(v);
        else      Cf[(size_t)row * ldc + col] = v;
      }
    }
}

// ---------------- split-K reduce: part[16][2048*128] fp32 -> xdbl bf16 ----------------
__global__ __launch_bounds__(256) void xdbl_reduce(
    const float* __restrict__ part, unsigned short* __restrict__ xdbl)
{
  int i = (blockIdx.x * 256 + threadIdx.x) * 4;
  const int SL = 2048 * 128;
  float4 s = *(const float4*)&part[i];
  #pragma unroll
  for (int z = 1; z < 16; ++z) {
    float4 p = *(const float4*)&part[(size_t)z * SL + i];
    s.x += p.x; s.y += p.y; s.z += p.z; s.w += p.w;
  }
  ushort4 ob;
  ob.x = f2bf(s.x); ob.y = f2bf(s.y); ob.z = f2bf(s.z); ob.w = f2bf(s.w);
  *(ushort4*)&xdbl[i] = ob;
}

// ---------------- final split-K reduce + residual ----------------
__global__ __launch_bounds__(256) void out_reduce(
    const float* __restrict__ part, const float* __restrict__ x,
    float* __restrict__ out)
{
  int i = (blockIdx.x * 256 + threadIdx.x) * 4;
  const int SL = 2048 * 1024;
  float4 a = *(const float4*)&part[i];
  float4 b = *(const float4*)&part[SL + i];
  float4 r = *(const float4*)&x[i];
  float4 o;
  o.x = a.x + b.x + r.x; o.y = a.y + b.y + r.y;
  o.z = a.z + b.z + r.z; o.w = a.w + b.w + r.w;
  *(float4*)&out[i] = o;
}

// ---------------- causal conv4 + SiLU on transposed layout ----------------
__global__ __launch_bounds__(256) void conv_silu_kernel(
    const unsigned short* __restrict__ xrT,
    const float* __restrict__ Wc, const float* __restrict__ bc,
    unsigned short* __restrict__ u2T)
{
  int d = blockIdx.x;
  int l0 = blockIdx.y * 1024 + threadIdx.x * 4;
  const unsigned short* ur = xrT + (size_t)d * L_SEQ;
  float w0 = Wc[0 * DI + d], w1 = Wc[1 * DI + d];
  float w2 = Wc[2 * DI + d], w3 = Wc[3 * DI + d];
  float b = bc[d];
  ushort4 v0 = *(const ushort4*)&ur[l0];
  ushort4 vm; vm.x = vm.y = vm.z = vm.w = 0;
  if (l0 > 0) vm = *(const ushort4*)&ur[l0 - 4];
  float um3 = bf2f(vm.y), um2 = bf2f(vm.z), um1 = bf2f(vm.w);
  float x0 = bf2f(v0.x), x1 = bf2f(v0.y), x2 = bf2f(v0.z), x3 = bf2f(v0.w);
  float y0 = b + w0 * um3 + w1 * um2 + w2 * um1 + w3 * x0;
  float y1 = b + w0 * um2 + w1 * um1 + w2 * x0  + w3 * x1;
  float y2 = b + w0 * um1 + w1 * x0  + w2 * x1  + w3 * x2;
  float y3 = b + w0 * x0  + w1 * x1  + w2 * x2  + w3 * x3;
  ushort4 ob;
  ob.x = f2bf(y0 / (1.f + __expf(-y0)));
  ob.y = f2bf(y1 / (1.f + __expf(-y1)));
  ob.z = f2bf(y2 / (1.f + __expf(-y2)));
  ob.w = f2bf(y3 / (1.f + __expf(-y3)));
  *(ushort4*)&u2T[(size_t)d * L_SEQ + l0] = ob;
}

// ================= segmented selective scan v3 =================
// NSEG=32 segments of 64. 128 threads = 8 ch x 16 states; one chunk/block.
// pass1: per-segment (prod dA, h_end | h0=0).  pass2: serial prefix over
// segment summaries -> h_in[s][d,n] (one thread per (d,n), coalesced).
// pass3: load h_in, scan 64 steps, y via fp16 LDS (32-step halves) post-pass.

__global__ __launch_bounds__(128) void scan_pass1(
    const unsigned short* __restrict__ deltaT, const unsigned short* __restrict__ u2T,
    const unsigned short* __restrict__ xdbl,
    const float* __restrict__ A_log,
    float* __restrict__ hend, float* __restrict__ aprod)
{
  int t = threadIdx.x;
  int ch = t >> 4, n = t & 15;
  int li = (t & 15) * 4;
  int d0 = blockIdx.x * 8, d = d0 + ch;
  int base = blockIdx.y * SEGLEN;

  __shared__ __align__(16) float sdT[8][68], suT[8][68], sBT[16][68];

  float An = -__expf(A_log[d * DS + n]);

  ushort4 rdu = *(const ushort4*)&deltaT[(size_t)d * L_SEQ + base + li];
  ushort4 ru  = *(const ushort4*)&u2T[(size_t)d * L_SEQ + base + li];
  ushort4 rB[2];
  #pragma unroll
  for (int q = 0; q < 2; ++q) {
    int ll = base + (t >> 2) + q * 32;
    rB[q] = *(const ushort4*)&xdbl[(size_t)ll * 128 + 64 + (t & 3) * 4];
  }

  float d0v = bf2f(rdu.x), d1v = bf2f(rdu.y), d2v = bf2f(rdu.z), d3v = bf2f(rdu.w);
  sdT[ch][li + 0] = d0v; sdT[ch][li + 1] = d1v;
  sdT[ch][li + 2] = d2v; sdT[ch][li + 3] = d3v;
  suT[ch][li + 0] = d0v * bf2f(ru.x); suT[ch][li + 1] = d1v * bf2f(ru.y);
  suT[ch][li + 2] = d2v * bf2f(ru.z); suT[ch][li + 3] = d3v * bf2f(ru.w);
  #pragma unroll
  for (int q = 0; q < 2; ++q) {
    int ll = (t >> 2) + q * 32;
    int nb = (t & 3) * 4;
    sBT[nb + 0][ll] = bf2f(rB[q].x); sBT[nb + 1][ll] = bf2f(rB[q].y);
    sBT[nb + 2][ll] = bf2f(rB[q].z); sBT[nb + 3][ll] = bf2f(rB[q].w);
  }
  __syncthreads();

  float h = 0.f, P = 1.f;
  #pragma unroll
  for (int g = 0; g < 64; g += 4) {
    float4 dl4 = *(const float4*)&sdT[ch][g];
    float4 du4 = *(const float4*)&suT[ch][g];
    float4 Bn4 = *(const float4*)&sBT[n][g];
    float dl[4] = {dl4.x, dl4.y, dl4.z, dl4.w};
    float du[4] = {du4.x, du4.y, du4.z, du4.w};
    float Bn[4] = {Bn4.x, Bn4.y, Bn4.z, Bn4.w};
    #pragma unroll
    for (int i = 0; i < 4; ++i) {
      float dA = __expf(dl[i] * An);
      P *= dA;
      h = dA * h + du[i] * Bn[i];
    }
  }
  size_t idx = (size_t)blockIdx.y * NSTATE + d0 * DS + t;
  hend[idx]  = h;
  aprod[idx] = P;
}

// ---- pass 2: prefix over segment summaries -> h_in ----
__global__ __launch_bounds__(256) void scan_pass2(
    const float* __restrict__ hend, const float* __restrict__ aprod,
    float* __restrict__ h_in)
{
  int i = blockIdx.x * 256 + threadIdx.x;   // over NSTATE
  float h = 0.f;
  h_in[i] = 0.f;
  for (int s = 0; s < NSEG - 1; ++s) {
    h = aprod[(size_t)s * NSTATE + i] * h + hend[(size_t)s * NSTATE + i];
    h_in[(size_t)(s + 1) * NSTATE + i] = h;
  }
}

// ---- pass 3: full scan per segment with precomputed h_in ----
__global__ __launch_bounds__(128) void scan_pass3(
    const unsigned short* __restrict__ deltaT, const unsigned short* __restrict__ u2T,
    const unsigned short* __restrict__ resT,
    const unsigned short* __restrict__ xdbl,
    const float* __restrict__ A_log, const float* __restrict__ Dp,
    const float* __restrict__ h_in,
    unsigned short* __restrict__ ybT)
{
  int t = threadIdx.x;
  int ch = t >> 4, n = t & 15;
  int li = (t & 15) * 4;
  int d0 = blockIdx.x * 8, d = d0 + ch;
  int s = blockIdx.y;
  int base = s * SEGLEN;

  __shared__ __align__(16) float sdT[8][68], suT[8][68];
  __shared__ __align__(16) float sBT[16][68], sCT[16][68];
  __shared__ __align__(4) _Float16 svh[32][134];

  float An = -__expf(A_log[d * DS + n]);
  float h = h_in[(size_t)s * NSTATE + d0 * DS + t];

  ushort4 rdu = *(const ushort4*)&deltaT[(size_t)d * L_SEQ + base + li];
  ushort4 ru  = *(const ushort4*)&u2T[(size_t)d * L_SEQ + base + li];
  ushort4 rB[2], rC[2];
  #pragma unroll
  for (int q = 0; q < 2; ++q) {
    int ll = base + (t >> 2) + q * 32;
    int n4 = (t & 3) * 4;
    rB[q] = *(const ushort4*)&xdbl[(size_t)ll * 128 + 64 + n4];
    rC[q] = *(const ushort4*)&xdbl[(size_t)ll * 128 + 80 + n4];
  }

  float d0v = bf2f(rdu.x), d1v = bf2f(rdu.y), d2v = bf2f(rdu.z), d3v = bf2f(rdu.w);
  sdT[ch][li + 0] = d0v; sdT[ch][li + 1] = d1v;
  sdT[ch][li + 2] = d2v; sdT[ch][li + 3] = d3v;
  suT[ch][li + 0] = d0v * bf2f(ru.x); suT[ch][li + 1] = d1v * bf2f(ru.y);
  suT[ch][li + 2] = d2v * bf2f(ru.z); suT[ch][li + 3] = d3v * bf2f(ru.w);
  #pragma unroll
  for (int q = 0; q < 2; ++q) {
    int ll = (t >> 2) + q * 32;
    int nb = (t & 3) * 4;
    sBT[nb + 0][ll] = bf2f(rB[q].x); sBT[nb + 1][ll] = bf2f(rB[q].y);
    sBT[nb + 2][ll] = bf2f(rB[q].z); sBT[nb + 3][ll] = bf2f(rB[q].w);
    sCT[nb + 0][ll] = bf2f(rC[q].x); sCT[nb + 1][ll] = bf2f(rC[q].y);
    sCT[nb + 2][ll] = bf2f(rC[q].z); sCT[nb + 3][ll] = bf2f(rC[q].w);
  }
  __syncthreads();

  #pragma unroll
  for (int half = 0; half < 2; ++half) {
    int g0 = half * 32;
    #pragma unroll
    for (int g = g0; g < g0 + 32; g += 4) {
      float4 dl4 = *(const float4*)&sdT[ch][g];
      float4 du4 = *(const float4*)&suT[ch][g];
      float4 Bn4 = *(const float4*)&sBT[n][g];
      float4 Cn4 = *(const float4*)&sCT[n][g];
      float dl[4] = {dl4.x, dl4.y, dl4.z, dl4.w};
      float du[4] = {du4.x, du4.y, du4.z, du4.w};
      float Bn[4] = {Bn4.x, Bn4.y, Bn4.z, Bn4.w};
      float Cn[4] = {Cn4.x, Cn4.y, Cn4.z, Cn4.w};
      #pragma unroll
      for (int i = 0; i < 4; ++i) {
        float dA = __expf(dl[i] * An);
        h = dA * h + du[i] * Bn[i];
        svh[g - g0 + i][t] = (_Float16)(h * Cn[i]);
      }
    }
    __syncthreads();

    // post-pass over 32 steps: 32 ll x 8 ch = 256 outputs / 128 threads
    #pragma unroll
    for (int r = 0; r < 2; ++r) {
      int idx = r * 128 + t;
      int ll = idx & 31, c2 = idx >> 5;
      const _Float16* row = &svh[ll][c2 * 16];
      float sum = 0.f;
      #pragma unroll
      for (int k = 0; k < 8; ++k) {
        h16x2 pv = *(const h16x2*)&row[k * 2];
        sum += (float)pv.x + (float)pv.y;
      }
      int dd = d0 + c2;
      int lg = base + g0 + ll;
      float uv = bf2f(u2T[(size_t)dd * L_SEQ + lg]);
      float rv = bf2f(resT[(size_t)dd * L_SEQ + lg]);
      float sig = 1.f / (1.f + __expf(-rv));
      float yv = (sum + uv * Dp[dd]) * rv * sig;
      ybT[(size_t)dd * L_SEQ + lg] = f2bf(yv);
    }
    __syncthreads();
  }
}

// ---------------- launch ----------------
extern "C" void kernel_launch(void* const* d_in, const int* in_sizes, int n_in,
                              void* d_out, int out_size, void* d_ws, size_t ws_size,
                              hipStream_t stream)
{
  const float* x      = (const float*)d_in[0];
  const float* W_in   = (const float*)d_in[1];
  const float* W_conv = (const float*)d_in[2];
  const float* b_conv = (const float*)d_in[3];
  const float* W_x    = (const float*)d_in[4];
  const float* W_dt   = (const float*)d_in[5];
  const float* b_dt   = (const float*)d_in[6];
  const float* A_log  = (const float*)d_in[7];
  const float* Dp     = (const float*)d_in[8];
  const float* W_out  = (const float*)d_in[9];
  const float* ln_s   = (const float*)d_in[10];
  const float* ln_b   = (const float*)d_in[11];

  char* ws = (char*)d_ws;
  const size_t MB = 1u << 20;
  unsigned short* xnb    = (unsigned short*)(ws);               // 0-4
  unsigned short* xrT    = (unsigned short*)(ws + 4 * MB);      // 4-20: bf16 [4096][2048]
  unsigned short* u2T    = (unsigned short*)(ws + 20 * MB);     // 20-28
  unsigned short* u2b    = (unsigned short*)(ws + 28 * MB);     // 28-36 (dead after xdbl gemm)
  float*          hend   = (float*)(ws + 28 * MB);              // 4 MB [32][32768], aliases u2b
  float*          aprod  = (float*)(ws + 32 * MB);              // 4 MB, aliases u2b
  unsigned short* xdbl   = (unsigned short*)(ws + 36 * MB);     // 0.5 MB
  unsigned short* Wxt    = (unsigned short*)(ws + 36 * MB + 512 * 1024); // 0.5 MB
  unsigned short* Wdt_t  = (unsigned short*)(ws + 37 * MB);     // 0.25 MB
  unsigned short* deltaTb= (unsigned short*)(ws + 38 * MB);     // 38-46: bf16 [2048][2048]
  unsigned short* Wtin   = (unsigned short*)(ws + 38 * MB);     // aliases deltaTb
  float*          part   = (float*)(ws + 46 * MB);              // 46-62: split-K partials
  unsigned short* ybT    = (unsigned short*)(ws + 54 * MB);     // 54-62
  float*          h_in   = (float*)(ws + 62 * MB);              // 62-66: [32][32768] fp32
  unsigned short* yb     = (unsigned short*)(ws + 4 * MB);      // aliases dead uT rows of xrT
  unsigned short* Wtout  = xnb;
  const unsigned short* resT = xrT + (size_t)DI * L_SEQ;        // rows [2048,4096)

  ln_kernel<<<L_SEQ, 256, 0, stream>>>(x, ln_s, ln_b, xnb);

  trans_bf16<<<dim3((2 * DI) / 64, DM / 64), 256, 0, stream>>>(W_in, Wtin, DM, 2 * DI);

  gemm2<64, 128, 0, 1, 1><<<dim3(L_SEQ / 128, (2 * DI) / 64), 256, 0, stream>>>(
      Wtin, DM, xnb, DM, xrT, L_SEQ, 2 * DI, L_SEQ, DM, nullptr);

  conv_silu_kernel<<<dim3(DI, 2), 256, 0, stream>>>(xrT, W_conv, b_conv, u2T);

  transpose_b16<<<dim3(L_SEQ / 64, DI / 64), 256, 0, stream>>>(u2T, u2b, DI, L_SEQ);

  trans_wx<<<(128 * 2048) / 256, 256, 0, stream>>>(W_x, Wxt);

  gemm2<64, 128, 0, 0, 16><<<dim3(1, L_SEQ / 64, 16), 256, 0, stream>>>(
      u2b, DI, Wxt, DI, part, 128, L_SEQ, 128, DI, nullptr);

  xdbl_reduce<<<(L_SEQ * 128) / 1024, 256, 0, stream>>>(part, xdbl);

  trans_bf16<<<dim3(DI / 64, DTR / 64), 256, 0, stream>>>(W_dt, Wdt_t, DTR, DI);

  gemm2<64, 128, 1, 1, 1><<<dim3(L_SEQ / 128, DI / 64), 256, 0, stream>>>(
      Wdt_t, DTR, xdbl, 128, deltaTb, L_SEQ, DI, L_SEQ, DTR, b_dt);

  trans_bf16<<<dim3(DM / 64, DI / 64), 256, 0, stream>>>(W_out, Wtout, DI, DM);

  // pass1 skips the last segment (summary never consumed)
  scan_pass1<<<dim3(DI / 8, NSEG - 1), 128, 0, stream>>>(
      deltaTb, u2T, xdbl, A_log, hend, aprod);

  scan_pass2<<<NSTATE / 256, 256, 0, stream>>>(hend, aprod, h_in);

  scan_pass3<<<dim3(DI / 8, NSEG), 128, 0, stream>>>(
      deltaTb, u2T, resT, xdbl, A_log, Dp, h_in, ybT);

  transpose_b16<<<dim3(L_SEQ / 64, DI / 64), 256, 0, stream>>>(ybT, yb, DI, L_SEQ);

  gemm2<64, 64, 0, 0, 2><<<dim3(DM / 64, L_SEQ / 64, 2), 256, 0, stream>>>(
      yb, DI, Wtout, DI, part, DM, L_SEQ, DM, DI, nullptr);

  out_reduce<<<(L_SEQ * DM) / 1024, 256, 0, stream>>>(part, x, (float*)d_out);
}